// Round 1
// baseline (2154.549 us; speedup 1.0000x reference)
//
#include <hip/hip_runtime.h>

#define EPS_BN 1e-5f

// ---------------- workspace layout (floats) ----------------
// Fused weights Wt[i] : COUT x (CIN*27), row-major
//   sizes: 1944, 31104, 124416, 497664, 1990656  (cum: 0,1944,33048,157464,655128)
// actA / actB ping-pong : 2*24*16*56*56 = 2408448 floats each (max layer)
// st   : per-channel scale/shift, 2*384 = 768
// h1   : fc1 output, 2*512 = 1024
static const size_t WT_OFF[5] = {0, 1944, 33048, 157464, 655128};
static const size_t WT_TOT   = 2645784;
static const size_t ACTA_OFF = WT_TOT;                    // 2645784
static const size_t ACTB_OFF = ACTA_OFF + 2408448;        // 5054232
static const size_t ST_OFF   = ACTB_OFF + 2408448;        // 7462680
static const size_t H1_OFF   = ST_OFF + 768;              // 7463448
static const size_t WS_TOT   = H1_OFF + 1024;             // 7464472 floats ~ 29.9 MB

__device__ __align__(256) float g_ws[WS_TOT];

// ---------------- fuse: Wt[o][k] = sum_p proj[p][k] * alpha[p][o] ----------------
__global__ __launch_bounds__(256) void fuse_w(const float* __restrict__ proj,
                                              const float* __restrict__ alpha,
                                              float* __restrict__ Wt,
                                              int K, int COUT)
{
    __shared__ float sa[16][17];  // [p][o]
    __shared__ float sp[16][17];  // [p][k]
    const int tx = threadIdx.x, ty = threadIdx.y;
    const int ko = blockIdx.x * 16 + tx;
    const int oo = blockIdx.y * 16 + ty;
    const int o_l = blockIdx.y * 16 + tx;
    float acc = 0.f;
    for (int p0 = 0; p0 < 512; p0 += 16) {
        sa[ty][tx] = (o_l < COUT) ? alpha[(size_t)(p0 + ty) * COUT + o_l] : 0.f;
        sp[ty][tx] = (ko < K)     ? proj [(size_t)(p0 + ty) * K    + ko ] : 0.f;
        __syncthreads();
        #pragma unroll
        for (int pp = 0; pp < 16; ++pp)
            acc = fmaf(sa[pp][ty], sp[pp][tx], acc);
        __syncthreads();
    }
    if (ko < K && oo < COUT)
        Wt[(size_t)oo * K + ko] = acc;
}

// ---------------- conv3d(3x3x3,pad1) + clamp(1+x,0) + maxpool(1,2,2) ----------------
// grid.x = B*16*Hp*Wp (one pooled position), grid.y = ceil(COUT/64), block = 64
__global__ __launch_bounds__(64) void conv_pool(const float* __restrict__ x,
                                                const float* __restrict__ Wt,
                                                float* __restrict__ out,
                                                int CIN, int COUT, int H, int W,
                                                int Hp, int Wp)
{
    extern __shared__ float patch[]; // CIN * 48  ([cin][dz(3)][dy(4)][dx(4)])
    int pos = blockIdx.x;
    const int pw = pos % Wp; pos /= Wp;
    const int ph = pos % Hp; pos /= Hp;
    const int d  = pos & 15;
    const int b  = pos >> 4;
    const int tid = threadIdx.x;
    const int h0 = 2 * ph - 1, w0 = 2 * pw - 1, d0 = d - 1;
    const int HW = H * W;

    const int nstage = CIN * 48;
    for (int i = tid; i < nstage; i += 64) {
        const int cin = i / 48;
        const int r   = i - cin * 48;
        const int dz = r >> 4;
        const int dy = (r & 15) >> 2;
        const int dx = r & 3;
        const int zz = d0 + dz, yy = h0 + dy, xx = w0 + dx;
        float v = 0.f;
        if ((unsigned)zz < 16u && (unsigned)yy < (unsigned)H && (unsigned)xx < (unsigned)W)
            v = x[(((size_t)b * CIN + cin) * 16 + zz) * (size_t)HW + yy * W + xx];
        patch[i] = v;
    }
    __syncthreads();

    const int oc = blockIdx.y * 64 + tid;
    if (oc >= COUT) return;
    const int K = CIN * 27;
    const float* __restrict__ wrow = Wt + (size_t)oc * K;

    float a00 = 0.f, a01 = 0.f, a10 = 0.f, a11 = 0.f;
    for (int cin = 0; cin < CIN; ++cin) {
        const float* pr = patch + cin * 48;
        const float* wb = wrow + cin * 27;
        #pragma unroll
        for (int kz = 0; kz < 3; ++kz) {
            float p[16];
            #pragma unroll
            for (int j = 0; j < 16; ++j) p[j] = pr[kz * 16 + j];
            float wv[9];
            #pragma unroll
            for (int j = 0; j < 9; ++j) wv[j] = wb[kz * 9 + j];
            #pragma unroll
            for (int ky = 0; ky < 3; ++ky) {
                #pragma unroll
                for (int kx = 0; kx < 3; ++kx) {
                    const float w = wv[ky * 3 + kx];
                    a00 = fmaf(w, p[ ky      * 4 + kx    ], a00);
                    a01 = fmaf(w, p[ ky      * 4 + kx + 1], a01);
                    a10 = fmaf(w, p[(ky + 1) * 4 + kx    ], a10);
                    a11 = fmaf(w, p[(ky + 1) * 4 + kx + 1], a11);
                }
            }
        }
    }
    const float v0 = fmaxf(1.f + a00, 0.f);
    const float v1 = fmaxf(1.f + a01, 0.f);
    const float v2 = fmaxf(1.f + a10, 0.f);
    const float v3 = fmaxf(1.f + a11, 0.f);
    const float m  = fmaxf(fmaxf(v0, v1), fmaxf(v2, v3));
    out[(((size_t)b * COUT + oc) * 16 + d) * (size_t)(Hp * Wp) + ph * Wp + pw] = m;
}

// ---------------- train-mode BN: per-channel scale/shift ----------------
__global__ __launch_bounds__(1024) void bn_stats(const float* __restrict__ act,
                                                 const float* __restrict__ gamma,
                                                 const float* __restrict__ beta,
                                                 float* __restrict__ st,
                                                 int C, int DHW)
{
    __shared__ float rs[1024];
    __shared__ float rq[1024];
    const int c = blockIdx.x, tid = threadIdx.x;
    float s = 0.f, q = 0.f;
    for (int b = 0; b < 2; ++b) {
        const float* p = act + ((size_t)b * C + c) * DHW;
        for (int i = tid; i < DHW; i += 1024) {
            const float v = p[i];
            s += v;
            q = fmaf(v, v, q);
        }
    }
    rs[tid] = s; rq[tid] = q;
    __syncthreads();
    for (int off = 512; off > 0; off >>= 1) {
        if (tid < off) { rs[tid] += rs[tid + off]; rq[tid] += rq[tid + off]; }
        __syncthreads();
    }
    if (tid == 0) {
        const float n    = 2.f * (float)DHW;
        const float mean = rs[0] / n;
        const float var  = rq[0] / n - mean * mean;
        const float sc   = gamma[c] * rsqrtf(var + EPS_BN);
        st[2 * c]     = sc;
        st[2 * c + 1] = fmaf(-mean, sc, beta[c]);
    }
}

__global__ __launch_bounds__(256) void bn_apply(float* __restrict__ act,
                                                const float* __restrict__ st,
                                                int C, int DHW, int total)
{
    const int i = blockIdx.x * 256 + threadIdx.x;
    if (i >= total) return;
    const int c = (i / DHW) % C;
    act[i] = fmaf(act[i], st[2 * c], st[2 * c + 1]);
}

// ---------------- fc1: (2,55296) @ w1^T(55296,512) + b1, relu ----------------
__global__ __launch_bounds__(256) void fc1_k(const float* __restrict__ h,
                                             const float* __restrict__ w1,
                                             const float* __restrict__ b1,
                                             float* __restrict__ hout)
{
    __shared__ float r0[256];
    __shared__ float r1[256];
    const int j = blockIdx.x, tid = threadIdx.x;
    const float* wr = w1 + (size_t)j * 55296;
    float a0 = 0.f, a1 = 0.f;
    for (int k = tid * 4; k < 55296; k += 1024) {
        const float4 w = *(const float4*)(wr + k);
        const float4 u = *(const float4*)(h + k);
        const float4 v = *(const float4*)(h + 55296 + k);
        a0 += w.x * u.x + w.y * u.y + w.z * u.z + w.w * u.w;
        a1 += w.x * v.x + w.y * v.y + w.z * v.z + w.w * v.w;
    }
    r0[tid] = a0; r1[tid] = a1;
    __syncthreads();
    for (int off = 128; off > 0; off >>= 1) {
        if (tid < off) { r0[tid] += r0[tid + off]; r1[tid] += r1[tid + off]; }
        __syncthreads();
    }
    if (tid == 0) {
        hout[j]       = fmaxf(r0[0] + b1[j], 0.f);
        hout[512 + j] = fmaxf(r1[0] + b1[j], 0.f);
    }
}

// ---------------- fc2 (relu) + fc3 fused in one block ----------------
__global__ __launch_bounds__(256) void fc23_k(const float* __restrict__ h1,
                                              const float* __restrict__ w2,
                                              const float* __restrict__ b2,
                                              const float* __restrict__ w3,
                                              const float* __restrict__ b3,
                                              float* __restrict__ out)
{
    __shared__ float h1s[1024];
    __shared__ float h2[512];
    const int tid = threadIdx.x;
    for (int i = tid; i < 1024; i += 256) h1s[i] = h1[i];
    __syncthreads();
    {   // fc2: 256 outputs per batch
        const float* wr = w2 + (size_t)tid * 512;
        #pragma unroll
        for (int b = 0; b < 2; ++b) {
            float a = 0.f;
            const float* hh = h1s + b * 512;
            for (int k = 0; k < 512; ++k) a = fmaf(wr[k], hh[k], a);
            h2[b * 256 + tid] = fmaxf(a + b2[tid], 0.f);
        }
    }
    __syncthreads();
    if (tid < 101) {
        const float* wr = w3 + (size_t)tid * 256;
        #pragma unroll
        for (int b = 0; b < 2; ++b) {
            float a = 0.f;
            const float* hh = h2 + b * 256;
            for (int k = 0; k < 256; ++k) a = fmaf(wr[k], hh[k], a);
            out[b * 101 + tid] = a + b3[tid];
        }
    }
}

// ---------------- host ----------------
extern "C" void kernel_launch(void* const* d_in, const int* in_sizes, int n_in,
                              void* d_out, int out_size, void* d_ws, size_t ws_size,
                              hipStream_t stream)
{
    const float* x  = (const float*)d_in[0];
    const float* p[5], *al[5], *g[5], *q[5];
    for (int i = 0; i < 5; ++i) {
        p[i]  = (const float*)d_in[1 + 4 * i];
        al[i] = (const float*)d_in[2 + 4 * i];
        g[i]  = (const float*)d_in[3 + 4 * i];
        q[i]  = (const float*)d_in[4 + 4 * i];
    }
    const float* w1 = (const float*)d_in[21];
    const float* b1 = (const float*)d_in[22];
    const float* w2 = (const float*)d_in[23];
    const float* b2 = (const float*)d_in[24];
    const float* w3 = (const float*)d_in[25];
    const float* b3 = (const float*)d_in[26];

    float* ws = nullptr;
    hipGetSymbolAddress((void**)&ws, HIP_SYMBOL(g_ws));

    float* Wt[5];
    for (int i = 0; i < 5; ++i) Wt[i] = ws + WT_OFF[i];
    float* actA = ws + ACTA_OFF;
    float* actB = ws + ACTB_OFF;
    float* st   = ws + ST_OFF;
    float* h1   = ws + H1_OFF;

    static const int KF[5] = {81, 648, 1296, 2592, 5184};
    static const int CO[5] = {24, 48, 96, 192, 384};

    // fuse projector+alpha into conv weights
    for (int i = 0; i < 5; ++i) {
        dim3 gb((KF[i] + 15) / 16, (CO[i] + 15) / 16);
        fuse_w<<<gb, dim3(16, 16), 0, stream>>>(p[i], al[i], Wt[i], KF[i], CO[i]);
    }

    // layer 1: (2,3,16,112,112) -> (2,24,16,56,56)
    conv_pool<<<dim3(2 * 16 * 56 * 56, 1), 64, 3 * 48 * 4, stream>>>(x, Wt[0], actA, 3, 24, 112, 112, 56, 56);
    bn_stats<<<24, 1024, 0, stream>>>(actA, g[0], q[0], st, 24, 16 * 56 * 56);
    bn_apply<<<(2408448 + 255) / 256, 256, 0, stream>>>(actA, st, 24, 16 * 56 * 56, 2408448);

    // layer 2: -> (2,48,16,28,28)
    conv_pool<<<dim3(2 * 16 * 28 * 28, 1), 64, 24 * 48 * 4, stream>>>(actA, Wt[1], actB, 24, 48, 56, 56, 28, 28);
    bn_stats<<<48, 1024, 0, stream>>>(actB, g[1], q[1], st, 48, 16 * 28 * 28);
    bn_apply<<<(1204224 + 255) / 256, 256, 0, stream>>>(actB, st, 48, 16 * 28 * 28, 1204224);

    // layer 3: -> (2,96,16,14,14)
    conv_pool<<<dim3(2 * 16 * 14 * 14, 2), 64, 48 * 48 * 4, stream>>>(actB, Wt[2], actA, 48, 96, 28, 28, 14, 14);
    bn_stats<<<96, 1024, 0, stream>>>(actA, g[2], q[2], st, 96, 16 * 14 * 14);
    bn_apply<<<(602112 + 255) / 256, 256, 0, stream>>>(actA, st, 96, 3136, 602112);

    // layer 4: -> (2,192,16,7,7)
    conv_pool<<<dim3(2 * 16 * 7 * 7, 3), 64, 96 * 48 * 4, stream>>>(actA, Wt[3], actB, 96, 192, 14, 14, 7, 7);
    bn_stats<<<192, 1024, 0, stream>>>(actB, g[3], q[3], st, 192, 784);
    bn_apply<<<(301056 + 255) / 256, 256, 0, stream>>>(actB, st, 192, 784, 301056);

    // layer 5: -> (2,384,16,3,3)
    conv_pool<<<dim3(2 * 16 * 3 * 3, 6), 64, 192 * 48 * 4, stream>>>(actB, Wt[4], actA, 192, 384, 7, 7, 3, 3);
    bn_stats<<<384, 1024, 0, stream>>>(actA, g[4], q[4], st, 384, 144);
    bn_apply<<<(110592 + 255) / 256, 256, 0, stream>>>(actA, st, 384, 144, 110592);

    // classifier head
    fc1_k<<<512, 256, 0, stream>>>(actA, w1, b1, h1);
    fc23_k<<<1, 256, 0, stream>>>(h1, w2, b2, w3, b3, (float*)d_out);
}

// Round 2
// 1959.371 us; speedup vs baseline: 1.0996x; 1.0996x over previous
//
#include <hip/hip_runtime.h>

#define EPS_BN 1e-5f

// ---------------- workspace layout (floats) ----------------
static const size_t WT_OFF[5] = {0, 1944, 33048, 157464, 655128};
static const size_t WT_TOT   = 2645784;
static const size_t ACTA_OFF = WT_TOT;                    // 2645784
static const size_t ACTB_OFF = ACTA_OFF + 2408448;        // 5054232
static const size_t ST_OFF   = ACTB_OFF + 2408448;        // 7462680
static const size_t H1_OFF   = ST_OFF + 768;              // 7463448
static const size_t WS_TOT   = H1_OFF + 1024;             // ~29.9 MB

__device__ __align__(256) float g_ws[WS_TOT];

// ---------------- fuse: Wt[o][k] = sum_p proj[p][k] * alpha[p][o] ----------------
// 128x128 tile, 8x8 per thread, P-chunks of 8.
__global__ __launch_bounds__(256) void fuse_w(const float* __restrict__ proj,
                                              const float* __restrict__ alpha,
                                              float* __restrict__ Wt, int K, int COUT)
{
    __shared__ __align__(16) float sa[8][128];  // [p][o]
    __shared__ __align__(16) float sp[8][128];  // [p][k]
    const int tid = threadIdx.x;
    const int tk = tid & 15, to = tid >> 4;
    const int kbase = blockIdx.x * 128;
    const int obase = blockIdx.y * 128;
    float acc[8][8];
    #pragma unroll
    for (int i = 0; i < 8; ++i)
        #pragma unroll
        for (int j = 0; j < 8; ++j) acc[i][j] = 0.f;

    for (int p0 = 0; p0 < 512; p0 += 8) {
        {
            const int i = tid * 4;
            const int pp = i >> 7, col = i & 127;
            const int o = obase + col;
            float4 va = make_float4(0.f, 0.f, 0.f, 0.f);
            if (o < COUT)  // COUT % 4 == 0 always, col % 4 == 0
                va = *(const float4*)(alpha + (size_t)(p0 + pp) * COUT + o);
            *(float4*)(&sa[pp][col]) = va;
            const int k = kbase + col;
            float4 vp = make_float4(0.f, 0.f, 0.f, 0.f);
            if ((K & 3) == 0) {
                if (k < K) vp = *(const float4*)(proj + (size_t)(p0 + pp) * K + k);
            } else {
                float t[4];
                #pragma unroll
                for (int j = 0; j < 4; ++j)
                    t[j] = (k + j < K) ? proj[(size_t)(p0 + pp) * K + k + j] : 0.f;
                vp = make_float4(t[0], t[1], t[2], t[3]);
            }
            *(float4*)(&sp[pp][col]) = vp;
        }
        __syncthreads();
        #pragma unroll
        for (int pp = 0; pp < 8; ++pp) {
            float a[8], bb[8];
            #pragma unroll
            for (int i = 0; i < 8; ++i) a[i] = sa[pp][to * 8 + i];
            #pragma unroll
            for (int j = 0; j < 8; ++j) bb[j] = sp[pp][tk + 16 * j];
            #pragma unroll
            for (int i = 0; i < 8; ++i)
                #pragma unroll
                for (int j = 0; j < 8; ++j)
                    acc[i][j] = fmaf(a[i], bb[j], acc[i][j]);
        }
        __syncthreads();
    }
    #pragma unroll
    for (int i = 0; i < 8; ++i) {
        const int o = obase + to * 8 + i;
        if (o < COUT) {
            #pragma unroll
            for (int j = 0; j < 8; ++j) {
                const int k = kbase + tk + 16 * j;
                if (k < K) Wt[(size_t)o * K + k] = acc[i][j];
            }
        }
    }
}

// ---------------- tiled conv3d(3x3x3,pad1) + BN-fold-in + clamp(1+x,0) + pool(1,2,2) ----------------
// Block: 256 threads = PT position-threads x OT oc-threads. Each thread: 1 pooled
// position (4 prepool accumulators) x OCR output channels. Input slab + weight
// chunk staged in LDS; k-loop over CIN/CINB chunks. BN of the PREVIOUS layer is
// applied during staging (st != nullptr).
template<int CIN, int COUT, int H, int W, int Hp, int Wp,
         int DT, int TPH, int TPW, int CINB, int OCB, int OCR, int PT>
__global__ __launch_bounds__(256) void conv_pool_t(
    const float* __restrict__ x, const float* __restrict__ Wt,
    const float* __restrict__ st, float* __restrict__ out)
{
    constexpr int ZR = DT + 2, YR = 2 * TPH + 2, XR = 2 * TPW + 2;
    constexpr int SLAB = CINB * ZR * YR * XR;
    constexpr int WCH = CINB * 27;
    constexpr int WSZ = OCB * WCH;
    constexpr int NKC = CIN / CINB;
    constexpr int K = CIN * 27;
    constexpr int HW = H * W;
    constexpr int TLH = (Hp + TPH - 1) / TPH;
    constexpr int TLW = (Wp + TPW - 1) / TPW;
    constexpr int TLD = 16 / DT;

    __shared__ __align__(16) float slab[SLAB];
    __shared__ __align__(16) float wl[WSZ];

    const int tid = threadIdx.x;
    const int pt = tid % PT;
    const int ot = tid / PT;

    int bx = blockIdx.x;
    const int tw = bx % TLW; bx /= TLW;
    const int th = bx % TLH; bx /= TLH;
    const int td = bx % TLD; bx /= TLD;
    const int b = bx;
    const int oc0 = blockIdx.y * OCB;

    const int ppw = pt % TPW;
    const int pph = (pt / TPW) % TPH;
    const int pd  = pt / (TPW * TPH);
    const int pw = tw * TPW + ppw;
    const int ph = th * TPH + pph;
    const int d  = td * DT + pd;

    const int d0 = td * DT - 1;
    const int y0 = 2 * th * TPH - 1;
    const int x0 = 2 * tw * TPW - 1;

    float acc[OCR][4];
    #pragma unroll
    for (int r = 0; r < OCR; ++r)
        #pragma unroll
        for (int j = 0; j < 4; ++j) acc[r][j] = 0.f;

    const float* wth = wl + ot * OCR * WCH;

    for (int kc = 0; kc < NKC; ++kc) {
        const int c0 = kc * CINB;
        // stage input slab (with BN fold of previous layer)
        for (int i = tid; i < SLAB; i += 256) {
            const int xx = i % XR;
            int t = i / XR;
            const int yy = t % YR; t /= YR;
            const int zz = t % ZR;
            const int cc = t / ZR;
            const int gz = d0 + zz, gy = y0 + yy, gx = x0 + xx;
            float v = 0.f;
            if ((unsigned)gz < 16u && (unsigned)gy < (unsigned)H && (unsigned)gx < (unsigned)W) {
                v = x[(((size_t)b * CIN + (c0 + cc)) * 16 + gz) * HW + gy * W + gx];
                if (st) v = fmaf(v, st[2 * (c0 + cc)], st[2 * (c0 + cc) + 1]);
            }
            slab[i] = v;
        }
        // stage weight chunk
        if constexpr ((WCH & 3) == 0 && (K & 3) == 0) {
            for (int i = tid * 4; i < WSZ; i += 1024) {
                const int o = i / WCH, j = i % WCH;
                *(float4*)(wl + i) = *(const float4*)(Wt + (size_t)(oc0 + o) * K + kc * WCH + j);
            }
        } else {
            for (int i = tid; i < WSZ; i += 256) {
                const int o = i / WCH, j = i % WCH;
                wl[i] = Wt[(size_t)(oc0 + o) * K + kc * WCH + j];
            }
        }
        __syncthreads();
        // compute
        #pragma unroll 1
        for (int c = 0; c < CINB; ++c) {
            const float* sl = slab + c * (ZR * YR * XR);
            #pragma unroll
            for (int kz = 0; kz < 3; ++kz) {
                const float* pr = sl + (pd + kz) * (YR * XR) + (2 * pph) * XR + 2 * ppw;
                float p[16];
                #pragma unroll
                for (int rr = 0; rr < 4; ++rr)
                    #pragma unroll
                    for (int cc2 = 0; cc2 < 4; ++cc2)
                        p[rr * 4 + cc2] = pr[rr * XR + cc2];
                #pragma unroll
                for (int r = 0; r < OCR; ++r) {
                    const float* wr = wth + r * WCH + c * 27 + kz * 9;
                    float w[9];
                    #pragma unroll
                    for (int j = 0; j < 9; ++j) w[j] = wr[j];
                    #pragma unroll
                    for (int ky = 0; ky < 3; ++ky)
                        #pragma unroll
                        for (int kx = 0; kx < 3; ++kx) {
                            const float wv = w[ky * 3 + kx];
                            acc[r][0] = fmaf(wv, p[ ky      * 4 + kx    ], acc[r][0]);
                            acc[r][1] = fmaf(wv, p[ ky      * 4 + kx + 1], acc[r][1]);
                            acc[r][2] = fmaf(wv, p[(ky + 1) * 4 + kx    ], acc[r][2]);
                            acc[r][3] = fmaf(wv, p[(ky + 1) * 4 + kx + 1], acc[r][3]);
                        }
                }
            }
        }
        __syncthreads();
    }
    // epilogue: clamp(1+x,0), 2x2 max, store
    if (ph < Hp && pw < Wp) {
        #pragma unroll
        for (int r = 0; r < OCR; ++r) {
            const int oc = oc0 + ot * OCR + r;
            const float v0 = fmaxf(1.f + acc[r][0], 0.f);
            const float v1 = fmaxf(1.f + acc[r][1], 0.f);
            const float v2 = fmaxf(1.f + acc[r][2], 0.f);
            const float v3 = fmaxf(1.f + acc[r][3], 0.f);
            out[(((size_t)b * COUT + oc) * 16 + d) * (Hp * Wp) + ph * Wp + pw] =
                fmaxf(fmaxf(v0, v1), fmaxf(v2, v3));
        }
    }
}

// ---------------- train-mode BN: per-channel scale/shift ----------------
__global__ __launch_bounds__(1024) void bn_stats(const float* __restrict__ act,
                                                 const float* __restrict__ gamma,
                                                 const float* __restrict__ beta,
                                                 float* __restrict__ st,
                                                 int C, int DHW)
{
    __shared__ float rs[1024];
    __shared__ float rq[1024];
    const int c = blockIdx.x, tid = threadIdx.x;
    float s = 0.f, q = 0.f;
    for (int b = 0; b < 2; ++b) {
        const float* p = act + ((size_t)b * C + c) * DHW;
        for (int i = tid; i < DHW; i += 1024) {
            const float v = p[i];
            s += v;
            q = fmaf(v, v, q);
        }
    }
    rs[tid] = s; rq[tid] = q;
    __syncthreads();
    for (int off = 512; off > 0; off >>= 1) {
        if (tid < off) { rs[tid] += rs[tid + off]; rq[tid] += rq[tid + off]; }
        __syncthreads();
    }
    if (tid == 0) {
        const float n    = 2.f * (float)DHW;
        const float mean = rs[0] / n;
        const float var  = rq[0] / n - mean * mean;
        const float sc   = gamma[c] * rsqrtf(var + EPS_BN);
        st[2 * c]     = sc;
        st[2 * c + 1] = fmaf(-mean, sc, beta[c]);
    }
}

__global__ __launch_bounds__(256) void bn_apply(float* __restrict__ act,
                                                const float* __restrict__ st,
                                                int C, int DHW, int total)
{
    const int i = blockIdx.x * 256 + threadIdx.x;
    if (i >= total) return;
    const int c = (i / DHW) % C;
    act[i] = fmaf(act[i], st[2 * c], st[2 * c + 1]);
}

// ---------------- fc1: (2,55296) @ w1^T + b1, relu ----------------
__global__ __launch_bounds__(256) void fc1_k(const float* __restrict__ h,
                                             const float* __restrict__ w1,
                                             const float* __restrict__ b1,
                                             float* __restrict__ hout)
{
    __shared__ float r0[256];
    __shared__ float r1[256];
    const int j = blockIdx.x, tid = threadIdx.x;
    const float* wr = w1 + (size_t)j * 55296;
    float a0 = 0.f, a1 = 0.f;
    for (int k = tid * 4; k < 55296; k += 1024) {
        const float4 w = *(const float4*)(wr + k);
        const float4 u = *(const float4*)(h + k);
        const float4 v = *(const float4*)(h + 55296 + k);
        a0 += w.x * u.x + w.y * u.y + w.z * u.z + w.w * u.w;
        a1 += w.x * v.x + w.y * v.y + w.z * v.z + w.w * v.w;
    }
    r0[tid] = a0; r1[tid] = a1;
    __syncthreads();
    for (int off = 128; off > 0; off >>= 1) {
        if (tid < off) { r0[tid] += r0[tid + off]; r1[tid] += r1[tid + off]; }
        __syncthreads();
    }
    if (tid == 0) {
        hout[j]       = fmaxf(r0[0] + b1[j], 0.f);
        hout[512 + j] = fmaxf(r1[0] + b1[j], 0.f);
    }
}

// ---------------- fc2 (relu) + fc3 fused ----------------
__global__ __launch_bounds__(256) void fc23_k(const float* __restrict__ h1,
                                              const float* __restrict__ w2,
                                              const float* __restrict__ b2,
                                              const float* __restrict__ w3,
                                              const float* __restrict__ b3,
                                              float* __restrict__ out)
{
    __shared__ float h1s[1024];
    __shared__ float h2[512];
    const int tid = threadIdx.x;
    for (int i = tid; i < 1024; i += 256) h1s[i] = h1[i];
    __syncthreads();
    {
        const float* wr = w2 + (size_t)tid * 512;
        #pragma unroll
        for (int b = 0; b < 2; ++b) {
            float a = 0.f;
            const float* hh = h1s + b * 512;
            for (int k = 0; k < 512; ++k) a = fmaf(wr[k], hh[k], a);
            h2[b * 256 + tid] = fmaxf(a + b2[tid], 0.f);
        }
    }
    __syncthreads();
    if (tid < 101) {
        const float* wr = w3 + (size_t)tid * 256;
        #pragma unroll
        for (int b = 0; b < 2; ++b) {
            float a = 0.f;
            const float* hh = h2 + b * 256;
            for (int k = 0; k < 256; ++k) a = fmaf(wr[k], hh[k], a);
            out[b * 101 + tid] = a + b3[tid];
        }
    }
}

// ---------------- host ----------------
extern "C" void kernel_launch(void* const* d_in, const int* in_sizes, int n_in,
                              void* d_out, int out_size, void* d_ws, size_t ws_size,
                              hipStream_t stream)
{
    const float* x  = (const float*)d_in[0];
    const float* p[5], *al[5], *g[5], *q[5];
    for (int i = 0; i < 5; ++i) {
        p[i]  = (const float*)d_in[1 + 4 * i];
        al[i] = (const float*)d_in[2 + 4 * i];
        g[i]  = (const float*)d_in[3 + 4 * i];
        q[i]  = (const float*)d_in[4 + 4 * i];
    }
    const float* w1 = (const float*)d_in[21];
    const float* b1 = (const float*)d_in[22];
    const float* w2 = (const float*)d_in[23];
    const float* b2 = (const float*)d_in[24];
    const float* w3 = (const float*)d_in[25];
    const float* b3 = (const float*)d_in[26];

    float* ws = nullptr;
    hipGetSymbolAddress((void**)&ws, HIP_SYMBOL(g_ws));

    float* Wt[5];
    for (int i = 0; i < 5; ++i) Wt[i] = ws + WT_OFF[i];
    float* actA = ws + ACTA_OFF;
    float* actB = ws + ACTB_OFF;
    float* st   = ws + ST_OFF;
    float* h1   = ws + H1_OFF;

    static const int KF[5] = {81, 648, 1296, 2592, 5184};
    static const int CO[5] = {24, 48, 96, 192, 384};

    for (int i = 0; i < 5; ++i) {
        dim3 gb((KF[i] + 127) / 128, (CO[i] + 127) / 128);
        fuse_w<<<gb, 256, 0, stream>>>(p[i], al[i], Wt[i], KF[i], CO[i]);
    }

    // L1: (2,3,16,112,112) -> (2,24,16,56,56)
    conv_pool_t<3, 24, 112, 112, 56, 56, 1, 8, 8, 3, 24, 6, 64>
        <<<dim3(2 * 16 * 7 * 7, 1), 256, 0, stream>>>(x, Wt[0], nullptr, actA);
    bn_stats<<<24, 1024, 0, stream>>>(actA, g[0], q[0], st, 24, 16 * 56 * 56);

    // L2: -> (2,48,16,28,28)   (BN of L1 folded into staging)
    conv_pool_t<24, 48, 56, 56, 28, 28, 1, 4, 4, 8, 48, 3, 16>
        <<<dim3(2 * 16 * 7 * 7, 1), 256, 0, stream>>>(actA, Wt[1], st, actB);
    bn_stats<<<48, 1024, 0, stream>>>(actB, g[1], q[1], st, 48, 16 * 28 * 28);

    // L3: -> (2,96,16,14,14)
    conv_pool_t<48, 96, 28, 28, 14, 14, 1, 4, 4, 8, 48, 3, 16>
        <<<dim3(2 * 16 * 4 * 4, 2), 256, 0, stream>>>(actB, Wt[2], st, actA);
    bn_stats<<<96, 1024, 0, stream>>>(actA, g[2], q[2], st, 96, 16 * 14 * 14);

    // L4: -> (2,192,16,7,7)
    conv_pool_t<96, 192, 14, 14, 7, 7, 1, 4, 4, 8, 48, 3, 16>
        <<<dim3(2 * 16 * 2 * 2, 4), 256, 0, stream>>>(actA, Wt[3], st, actB);
    bn_stats<<<192, 1024, 0, stream>>>(actB, g[3], q[3], st, 192, 784);

    // L5: -> (2,384,16,3,3)
    conv_pool_t<192, 384, 7, 7, 3, 3, 4, 2, 2, 8, 32, 2, 16>
        <<<dim3(2 * 4 * 2 * 2, 12), 256, 0, stream>>>(actB, Wt[4], st, actA);
    bn_stats<<<384, 1024, 0, stream>>>(actA, g[4], q[4], st, 384, 144);
    bn_apply<<<(110592 + 255) / 256, 256, 0, stream>>>(actA, st, 384, 144, 110592);

    // head
    fc1_k<<<512, 256, 0, stream>>>(actA, w1, b1, h1);
    fc23_k<<<1, 256, 0, stream>>>(h1, w2, b2, w3, b3, (float*)d_out);
}

// Round 3
// 1521.127 us; speedup vs baseline: 1.4164x; 1.2881x over previous
//
#include <hip/hip_runtime.h>

#define EPS_BN 1e-5f

typedef __attribute__((ext_vector_type(8))) short sh8;
typedef __attribute__((ext_vector_type(4))) float f32x4;

// ---------------- workspace (floats) ----------------
static const size_t ACTA_OFF = 0;                 // 2408448
static const size_t ACTB_OFF = 2408448;           // 2408448
static const size_t ST_OFF   = 4816896;           // 768
static const size_t H1_OFF   = 4817664;           // 1024
static const size_t PART_OFF = 4818688;           // 6*1152*384 = 2654208
static const size_t WS_TOT   = 7472896;           // ~29.9 MB

__device__ __align__(256) float g_ws[WS_TOT];

// bf16 fused conv weights, [NPAD][KPAD] per layer, zero-padded
static const size_t WB_OFF[5] = {0, 3072, 35328, 161280, 658944};
__device__ __align__(256) unsigned short g_wb[2649600];   // ~5.3 MB

__device__ inline unsigned short f2bf(float v) {
    unsigned u = __float_as_uint(v);
    return (unsigned short)((u + 0x7fffu + ((u >> 16) & 1u)) >> 16);
}

// ---------------- fuse: Wb[o][k] = bf16( sum_p proj[p][k] * alpha[p][o] ) ----------------
__global__ __launch_bounds__(256) void fuse_w(const float* __restrict__ proj,
                                              const float* __restrict__ alpha,
                                              unsigned short* __restrict__ Wb,
                                              int K, int COUT, int KPAD, int NPAD)
{
    __shared__ __align__(16) float sa[8][128];  // [p][o]
    __shared__ __align__(16) float sp[8][128];  // [p][k]
    const int tid = threadIdx.x;
    const int tk = tid & 15, to = tid >> 4;
    const int kbase = blockIdx.x * 128;
    const int obase = blockIdx.y * 128;
    float acc[8][8];
    #pragma unroll
    for (int i = 0; i < 8; ++i)
        #pragma unroll
        for (int j = 0; j < 8; ++j) acc[i][j] = 0.f;

    for (int p0 = 0; p0 < 512; p0 += 8) {
        {
            const int i = tid * 4;
            const int pp = i >> 7, col = i & 127;
            const int o = obase + col;
            float4 va = make_float4(0.f, 0.f, 0.f, 0.f);
            if (o < COUT)
                va = *(const float4*)(alpha + (size_t)(p0 + pp) * COUT + o);
            *(float4*)(&sa[pp][col]) = va;
            const int k = kbase + col;
            float4 vp = make_float4(0.f, 0.f, 0.f, 0.f);
            if ((K & 3) == 0) {
                if (k < K) vp = *(const float4*)(proj + (size_t)(p0 + pp) * K + k);
            } else {
                float t[4];
                #pragma unroll
                for (int j = 0; j < 4; ++j)
                    t[j] = (k + j < K) ? proj[(size_t)(p0 + pp) * K + k + j] : 0.f;
                vp = make_float4(t[0], t[1], t[2], t[3]);
            }
            *(float4*)(&sp[pp][col]) = vp;
        }
        __syncthreads();
        #pragma unroll
        for (int pp = 0; pp < 8; ++pp) {
            float a[8], bb[8];
            #pragma unroll
            for (int i = 0; i < 8; ++i) a[i] = sa[pp][to * 8 + i];
            #pragma unroll
            for (int j = 0; j < 8; ++j) bb[j] = sp[pp][tk + 16 * j];
            #pragma unroll
            for (int i = 0; i < 8; ++i)
                #pragma unroll
                for (int j = 0; j < 8; ++j)
                    acc[i][j] = fmaf(a[i], bb[j], acc[i][j]);
        }
        __syncthreads();
    }
    #pragma unroll
    for (int i = 0; i < 8; ++i) {
        const int o = obase + to * 8 + i;
        if (o < NPAD) {
            #pragma unroll
            for (int j = 0; j < 8; ++j) {
                const int k = kbase + tk + 16 * j;
                if (k < KPAD) {
                    const float val = (o < COUT && k < K) ? acc[i][j] : 0.f;
                    Wb[(size_t)o * KPAD + k] = f2bf(val);
                }
            }
        }
    }
}

// ---------------- implicit-GEMM bf16 MFMA conv + clamp(1+x,0) + pool(1,2,2) ----------------
// M = 4 * (B*16*Hp*Wp) prepool positions, grouped 4-per-pooled-output.
// Block = 256 thr = 4 waves; block tile 64(M) x NBLK(N); K-step 32.
// A: im2col gather (BN of previous layer folded); B: direct from bf16 Wb.
template<int CIN, int COUT, int NPAD, int KPAD, int H, int W, int Hp, int Wp,
         int NBLK, int SPLIT, bool HAS_ST>
__global__ __launch_bounds__(256) void conv_mfma(
    const float* __restrict__ x, const unsigned short* __restrict__ Wb,
    const float* __restrict__ st, float* __restrict__ out)
{
    constexpr int NT = NBLK / 16;
    constexpr int K = CIN * 27;
    constexpr int HW = H * W;
    constexpr int NSTEP = KPAD / 32 / SPLIT;
    constexpr int MTOT = 2 * 16 * Hp * Wp * 4;

    __shared__ __align__(16) unsigned short As[64 * 40];
    __shared__ __align__(16) unsigned short Bs[NBLK * 40];
    __shared__ float sts[HAS_ST ? 2 * CIN : 1];

    const int tid = threadIdx.x;
    const int lane = tid & 63;
    const int wv = tid >> 6;
    const int blk_m = blockIdx.x;
    const int oc0 = blockIdx.y * NBLK;
    const int kc = (SPLIT > 1) ? blockIdx.z : 0;

    if (HAS_ST) {
        for (int i = tid; i < 2 * CIN; i += 256) sts[i] = st[i];
    }
    __syncthreads();

    // per-thread gather coords (fixed: this thread always gathers row m_l)
    const int m_l = tid & 63;
    const int oct = tid >> 6;           // k-octet 0..3
    const int m_g = blk_m * 64 + m_l;
    const int pooled = m_g >> 2, sub = m_g & 3;
    const int pw_g = pooled % Wp;
    const int ph_g = (pooled / Wp) % Hp;
    const int d_g  = (pooled / (Wp * Hp)) & 15;
    const int b_g  = pooled / (Wp * Hp * 16);
    const int h_g = 2 * ph_g + (sub >> 1);
    const int w_g = 2 * pw_g + (sub & 1);
    const float* __restrict__ xb = x + (size_t)b_g * CIN * 16 * HW;

    f32x4 acc[NT];
    #pragma unroll
    for (int i = 0; i < NT; ++i) acc[i] = (f32x4){0.f, 0.f, 0.f, 0.f};

    const int k_begin = kc * NSTEP * 32;

    for (int s = 0; s < NSTEP; ++s) {
        const int k0 = k_begin + s * 32;
        // ---- A gather: this thread fills one 8-element k-octet of row m_l
        {
            sh8 av;
            int kk = k0 + oct * 8;
            #pragma unroll
            for (int j = 0; j < 8; ++j, ++kk) {
                float v = 0.f;
                if (kk < K) {
                    const int cin = kk / 27;
                    int t = kk - cin * 27;
                    const int kz = t / 9; t -= kz * 9;
                    const int ky = t / 3;
                    const int kx = t - ky * 3;
                    const int zz = d_g + kz - 1, yy = h_g + ky - 1, xx = w_g + kx - 1;
                    if ((unsigned)zz < 16u && (unsigned)yy < (unsigned)H && (unsigned)xx < (unsigned)W) {
                        v = xb[((size_t)cin * 16 + zz) * HW + yy * W + xx];
                        if (HAS_ST) v = fmaf(v, sts[2 * cin], sts[2 * cin + 1]);
                    }
                }
                av[j] = (short)f2bf(v);
            }
            *(sh8*)&As[m_l * 40 + oct * 8] = av;
        }
        // ---- B stage: NBLK rows x 32 bf16, 16B chunks straight from global
        for (int i = tid; i < NBLK * 4; i += 256) {
            const int row = i >> 2, c = i & 3;
            *(sh8*)&Bs[row * 40 + c * 8] =
                *(const sh8*)&Wb[(size_t)(oc0 + row) * KPAD + k0 + c * 8];
        }
        __syncthreads();
        // ---- fragments + MFMA
        const sh8 af = *(const sh8*)&As[(wv * 16 + (lane & 15)) * 40 + (lane >> 4) * 8];
        #pragma unroll
        for (int nt = 0; nt < NT; ++nt) {
            const sh8 bf = *(const sh8*)&Bs[(nt * 16 + (lane & 15)) * 40 + (lane >> 4) * 8];
            acc[nt] = __builtin_amdgcn_mfma_f32_16x16x32_bf16(af, bf, acc[nt], 0, 0, 0);
        }
        __syncthreads();
    }

    const int q = lane >> 4;
    const int nloc = lane & 15;
    if (SPLIT == 1) {
        // each lane quad holds one pooled group (4 prepool values) in its 4 regs
        const int pooled_o = blk_m * 16 + wv * 4 + q;
        const int pwo = pooled_o % Wp;
        const int pho = (pooled_o / Wp) % Hp;
        const int dd  = (pooled_o / (Wp * Hp)) & 15;
        const int bb  = pooled_o / (Wp * Hp * 16);
        #pragma unroll
        for (int nt = 0; nt < NT; ++nt) {
            const int oc = oc0 + nt * 16 + nloc;
            if (oc < COUT) {
                float mx = fmaxf(1.f + acc[nt][0], 0.f);
                mx = fmaxf(mx, fmaxf(1.f + acc[nt][1], 0.f));
                mx = fmaxf(mx, fmaxf(1.f + acc[nt][2], 0.f));
                mx = fmaxf(mx, fmaxf(1.f + acc[nt][3], 0.f));
                out[(((size_t)bb * COUT + oc) * 16 + dd) * (Hp * Wp) + pho * Wp + pwo] = mx;
            }
        }
    } else {
        // raw partials: part[kc][m][oc]
        #pragma unroll
        for (int nt = 0; nt < NT; ++nt) {
            const int oc = oc0 + nt * 16 + nloc;
            #pragma unroll
            for (int r = 0; r < 4; ++r) {
                const int mm = blk_m * 64 + wv * 16 + q * 4 + r;
                out[((size_t)kc * MTOT + mm) * COUT + oc] = acc[nt][r];
            }
        }
    }
}

// ---------------- split-K reduce + clamp + pool epilogue ----------------
template<int COUT, int Hp, int Wp, int SPLIT>
__global__ __launch_bounds__(256) void pool_epi(const float* __restrict__ part,
                                                float* __restrict__ out)
{
    constexpr int PO = 2 * 16 * Hp * Wp;
    constexpr int M = PO * 4;
    const int idx = blockIdx.x * 256 + threadIdx.x;
    if (idx >= PO * COUT) return;
    const int oc = idx % COUT;
    const int p = idx / COUT;
    float v[4] = {0.f, 0.f, 0.f, 0.f};
    for (int s = 0; s < SPLIT; ++s)
        #pragma unroll
        for (int r = 0; r < 4; ++r)
            v[r] += part[((size_t)s * M + p * 4 + r) * COUT + oc];
    float mx = fmaxf(1.f + v[0], 0.f);
    mx = fmaxf(mx, fmaxf(1.f + v[1], 0.f));
    mx = fmaxf(mx, fmaxf(1.f + v[2], 0.f));
    mx = fmaxf(mx, fmaxf(1.f + v[3], 0.f));
    const int pwo = p % Wp;
    const int pho = (p / Wp) % Hp;
    const int dd  = (p / (Wp * Hp)) & 15;
    const int bb  = p / (Wp * Hp * 16);
    out[(((size_t)bb * COUT + oc) * 16 + dd) * (Hp * Wp) + pho * Wp + pwo] = mx;
}

// ---------------- train-mode BN stats ----------------
__global__ __launch_bounds__(1024) void bn_stats(const float* __restrict__ act,
                                                 const float* __restrict__ gamma,
                                                 const float* __restrict__ beta,
                                                 float* __restrict__ st,
                                                 int C, int DHW)
{
    __shared__ float rs[1024];
    __shared__ float rq[1024];
    const int c = blockIdx.x, tid = threadIdx.x;
    float s = 0.f, q = 0.f;
    for (int b = 0; b < 2; ++b) {
        const float* p = act + ((size_t)b * C + c) * DHW;
        for (int i = tid; i < DHW; i += 1024) {
            const float v = p[i];
            s += v;
            q = fmaf(v, v, q);
        }
    }
    rs[tid] = s; rq[tid] = q;
    __syncthreads();
    for (int off = 512; off > 0; off >>= 1) {
        if (tid < off) { rs[tid] += rs[tid + off]; rq[tid] += rq[tid + off]; }
        __syncthreads();
    }
    if (tid == 0) {
        const float n    = 2.f * (float)DHW;
        const float mean = rs[0] / n;
        const float var  = rq[0] / n - mean * mean;
        const float sc   = gamma[c] * rsqrtf(var + EPS_BN);
        st[2 * c]     = sc;
        st[2 * c + 1] = fmaf(-mean, sc, beta[c]);
    }
}

__global__ __launch_bounds__(256) void bn_apply(float* __restrict__ act,
                                                const float* __restrict__ st,
                                                int C, int DHW, int total)
{
    const int i = blockIdx.x * 256 + threadIdx.x;
    if (i >= total) return;
    const int c = (i / DHW) % C;
    act[i] = fmaf(act[i], st[2 * c], st[2 * c + 1]);
}

// ---------------- fc1 ----------------
__global__ __launch_bounds__(256) void fc1_k(const float* __restrict__ h,
                                             const float* __restrict__ w1,
                                             const float* __restrict__ b1,
                                             float* __restrict__ hout)
{
    __shared__ float r0[256];
    __shared__ float r1[256];
    const int j = blockIdx.x, tid = threadIdx.x;
    const float* wr = w1 + (size_t)j * 55296;
    float a0 = 0.f, a1 = 0.f;
    for (int k = tid * 4; k < 55296; k += 1024) {
        const float4 w = *(const float4*)(wr + k);
        const float4 u = *(const float4*)(h + k);
        const float4 v = *(const float4*)(h + 55296 + k);
        a0 += w.x * u.x + w.y * u.y + w.z * u.z + w.w * u.w;
        a1 += w.x * v.x + w.y * v.y + w.z * v.z + w.w * v.w;
    }
    r0[tid] = a0; r1[tid] = a1;
    __syncthreads();
    for (int off = 128; off > 0; off >>= 1) {
        if (tid < off) { r0[tid] += r0[tid + off]; r1[tid] += r1[tid + off]; }
        __syncthreads();
    }
    if (tid == 0) {
        hout[j]       = fmaxf(r0[0] + b1[j], 0.f);
        hout[512 + j] = fmaxf(r1[0] + b1[j], 0.f);
    }
}

// ---------------- fc2 (relu) + fc3 fused ----------------
__global__ __launch_bounds__(256) void fc23_k(const float* __restrict__ h1,
                                              const float* __restrict__ w2,
                                              const float* __restrict__ b2,
                                              const float* __restrict__ w3,
                                              const float* __restrict__ b3,
                                              float* __restrict__ out)
{
    __shared__ float h1s[1024];
    __shared__ float h2[512];
    const int tid = threadIdx.x;
    for (int i = tid; i < 1024; i += 256) h1s[i] = h1[i];
    __syncthreads();
    {
        const float* wr = w2 + (size_t)tid * 512;
        #pragma unroll
        for (int b = 0; b < 2; ++b) {
            float a = 0.f;
            const float* hh = h1s + b * 512;
            for (int k = 0; k < 512; ++k) a = fmaf(wr[k], hh[k], a);
            h2[b * 256 + tid] = fmaxf(a + b2[tid], 0.f);
        }
    }
    __syncthreads();
    if (tid < 101) {
        const float* wr = w3 + (size_t)tid * 256;
        #pragma unroll
        for (int b = 0; b < 2; ++b) {
            float a = 0.f;
            const float* hh = h2 + b * 256;
            for (int k = 0; k < 256; ++k) a = fmaf(wr[k], hh[k], a);
            out[b * 101 + tid] = a + b3[tid];
        }
    }
}

// ---------------- host ----------------
extern "C" void kernel_launch(void* const* d_in, const int* in_sizes, int n_in,
                              void* d_out, int out_size, void* d_ws, size_t ws_size,
                              hipStream_t stream)
{
    const float* x  = (const float*)d_in[0];
    const float* p[5], *al[5], *g[5], *q[5];
    for (int i = 0; i < 5; ++i) {
        p[i]  = (const float*)d_in[1 + 4 * i];
        al[i] = (const float*)d_in[2 + 4 * i];
        g[i]  = (const float*)d_in[3 + 4 * i];
        q[i]  = (const float*)d_in[4 + 4 * i];
    }
    const float* w1 = (const float*)d_in[21];
    const float* b1 = (const float*)d_in[22];
    const float* w2 = (const float*)d_in[23];
    const float* b2 = (const float*)d_in[24];
    const float* w3 = (const float*)d_in[25];
    const float* b3 = (const float*)d_in[26];

    float* ws = nullptr;
    hipGetSymbolAddress((void**)&ws, HIP_SYMBOL(g_ws));
    unsigned short* wb = nullptr;
    hipGetSymbolAddress((void**)&wb, HIP_SYMBOL(g_wb));

    float* actA = ws + ACTA_OFF;
    float* actB = ws + ACTB_OFF;
    float* st   = ws + ST_OFF;
    float* h1   = ws + H1_OFF;
    float* part = ws + PART_OFF;

    static const int KF[5]   = {81, 648, 1296, 2592, 5184};
    static const int KP[5]   = {96, 672, 1312, 2592, 5184};
    static const int CO[5]   = {24, 48, 96, 192, 384};
    static const int NP[5]   = {32, 48, 96, 192, 384};

    for (int i = 0; i < 5; ++i) {
        dim3 gb((KP[i] + 127) / 128, (NP[i] + 127) / 128);
        fuse_w<<<gb, 256, 0, stream>>>(p[i], al[i], wb + WB_OFF[i], KF[i], CO[i], KP[i], NP[i]);
    }

    // L1: (2,3,16,112,112) -> (2,24,16,56,56); M=401408 -> 6272 m-blocks
    conv_mfma<3, 24, 32, 96, 112, 112, 56, 56, 32, 1, false>
        <<<dim3(6272, 1), 256, 0, stream>>>(x, wb + WB_OFF[0], nullptr, actA);
    bn_stats<<<24, 1024, 0, stream>>>(actA, g[0], q[0], st, 24, 16 * 56 * 56);

    // L2: -> (2,48,16,28,28); M=100352 -> 1568
    conv_mfma<24, 48, 48, 672, 56, 56, 28, 28, 48, 1, true>
        <<<dim3(1568, 1), 256, 0, stream>>>(actA, wb + WB_OFF[1], st, actB);
    bn_stats<<<48, 1024, 0, stream>>>(actB, g[1], q[1], st, 48, 16 * 28 * 28);

    // L3: -> (2,96,16,14,14); M=25088 -> 392 x 2
    conv_mfma<48, 96, 96, 1312, 28, 28, 14, 14, 48, 1, true>
        <<<dim3(392, 2), 256, 0, stream>>>(actB, wb + WB_OFF[2], st, actA);
    bn_stats<<<96, 1024, 0, stream>>>(actA, g[2], q[2], st, 96, 16 * 14 * 14);

    // L4: -> (2,192,16,7,7); M=6272 -> 98 x 4
    conv_mfma<96, 192, 192, 2592, 14, 14, 7, 7, 48, 1, true>
        <<<dim3(98, 4), 256, 0, stream>>>(actA, wb + WB_OFF[3], st, actB);
    bn_stats<<<192, 1024, 0, stream>>>(actB, g[3], q[3], st, 192, 784);

    // L5: -> (2,384,16,3,3); M=1152 -> 18 x 6 x splitK6
    conv_mfma<192, 384, 384, 5184, 7, 7, 3, 3, 64, 6, true>
        <<<dim3(18, 6, 6), 256, 0, stream>>>(actB, wb + WB_OFF[4], st, part);
    pool_epi<384, 3, 3, 6><<<432, 256, 0, stream>>>(part, actA);
    bn_stats<<<384, 1024, 0, stream>>>(actA, g[4], q[4], st, 384, 144);
    bn_apply<<<(110592 + 255) / 256, 256, 0, stream>>>(actA, st, 384, 144, 110592);

    // head
    fc1_k<<<512, 256, 0, stream>>>(actA, w1, b1, h1);
    fc23_k<<<1, 256, 0, stream>>>(h1, w2, b2, w3, b3, (float*)d_out);
}

// Round 5
// 1338.998 us; speedup vs baseline: 1.6091x; 1.1360x over previous
//
#include <hip/hip_runtime.h>

#define EPS_BN 1e-5f

typedef __attribute__((ext_vector_type(8))) short sh8;
typedef __attribute__((ext_vector_type(4))) short sh4;
typedef __attribute__((ext_vector_type(4))) float f32x4;

// ================= fp32 workspace arena =================
static const size_t WF_OFF[5] = {0, 1944, 33048, 157464, 655128};  // fused fp32 weights [COUT][K]
static const size_t PART_OFF = 2645784;   // split-K partials (max 3*6272*192 = 3612672)
static const size_t PRE_OFF  = 6258456;   // pre-BN flat conv output (max 2408448)
static const size_t OUT5_OFF = 8666904;   // 110592 L5 pre-BN flat
static const size_t H_OFF    = 8777496;   // 110592 fc1 input (NCDHW flat)
static const size_t ST_OFF   = 8888088;   // 768 per-channel scale/shift
static const size_t BNP_OFF  = 8888856;   // 8192 bn partials
static const size_t H1_OFF   = 8897048;   // 1024 fc1 output
static const size_t WS_TOT   = 8898072;   // ~35.6 MB
__device__ __align__(256) float g_ws[WS_TOT];

// bf16 activation arena (halo-padded NDHWC), zeroed each launch
static const size_t XIN_OFF = 0;         // [2][18][114][114][4]  = 1871424
static const size_t A1_OFF  = 1871424;   // [2][18][58][58][24]   = 2905344
static const size_t A2_OFF  = 4776768;   // [2][18][30][30][48]   = 1555200
static const size_t A3_OFF  = 6331968;   // [2][18][16][16][96]   = 884736
static const size_t A4_OFF  = 7216704;   // [2][18][9][9][192]    = 559872
static const size_t AR_TOT  = 7776576;
__device__ __align__(256) unsigned short g_act[AR_TOT];

// bf16 conv weights [NPAD][KPAD], k-order = s*CPAD+c
static const size_t WB_OFF[5] = {0, 4096, 36352, 162304, 659968};
__device__ __align__(256) unsigned short g_wb[2650624];

__device__ inline unsigned short f2bf(float v) {
    unsigned u = __float_as_uint(v);
    return (unsigned short)((u + 0x7fffu + ((u >> 16) & 1u)) >> 16);
}

// ================= zero arena =================
__global__ __launch_bounds__(256) void zero16(int4* __restrict__ p, int n) {
    const int i = blockIdx.x * 256 + threadIdx.x;
    if (i < n) p[i] = make_int4(0, 0, 0, 0);
}

// ================= input: NCDHW fp32 -> halo NDHWC bf16 (Cpad=4) =================
__global__ __launch_bounds__(256) void convert_input(const float* __restrict__ x,
                                                     unsigned short* __restrict__ xp)
{
    const int i = blockIdx.x * 256 + threadIdx.x;
    if (i >= 2 * 18 * 114 * 114 * 4) return;
    const int c = i & 3;
    int t = i >> 2;
    const int xx = t % 114; t /= 114;
    const int yy = t % 114; t /= 114;
    const int zz = t % 18;
    const int b  = t / 18;
    float v = 0.f;
    if (c < 3 && (unsigned)(zz - 1) < 16u && (unsigned)(yy - 1) < 112u && (unsigned)(xx - 1) < 112u)
        v = x[(((size_t)b * 3 + c) * 16 + (zz - 1)) * 12544 + (yy - 1) * 112 + (xx - 1)];
    xp[i] = f2bf(v);
}

// ================= fuse: Wf[o][k] = sum_p proj[p][k] * alpha[p][o]  (fp32) =================
__global__ __launch_bounds__(256) void fuse_w(const float* __restrict__ proj,
                                              const float* __restrict__ alpha,
                                              float* __restrict__ Wf, int K, int COUT)
{
    __shared__ __align__(16) float sa[8][128];
    __shared__ __align__(16) float sp[8][128];
    const int tid = threadIdx.x;
    const int tk = tid & 15, to = tid >> 4;
    const int kbase = blockIdx.x * 128;
    const int obase = blockIdx.y * 128;
    float acc[8][8];
    #pragma unroll
    for (int i = 0; i < 8; ++i)
        #pragma unroll
        for (int j = 0; j < 8; ++j) acc[i][j] = 0.f;

    for (int p0 = 0; p0 < 512; p0 += 8) {
        {
            const int i = tid * 4;
            const int pp = i >> 7, col = i & 127;
            const int o = obase + col;
            float4 va = make_float4(0.f, 0.f, 0.f, 0.f);
            if (o < COUT)
                va = *(const float4*)(alpha + (size_t)(p0 + pp) * COUT + o);
            *(float4*)(&sa[pp][col]) = va;
            const int k = kbase + col;
            float t4[4];
            #pragma unroll
            for (int j = 0; j < 4; ++j)
                t4[j] = (k + j < K) ? proj[(size_t)(p0 + pp) * K + k + j] : 0.f;
            *(float4*)(&sp[pp][col]) = make_float4(t4[0], t4[1], t4[2], t4[3]);
        }
        __syncthreads();
        #pragma unroll
        for (int pp = 0; pp < 8; ++pp) {
            float a[8], bb[8];
            #pragma unroll
            for (int i = 0; i < 8; ++i) a[i] = sa[pp][to * 8 + i];
            #pragma unroll
            for (int j = 0; j < 8; ++j) bb[j] = sp[pp][tk + 16 * j];
            #pragma unroll
            for (int i = 0; i < 8; ++i)
                #pragma unroll
                for (int j = 0; j < 8; ++j)
                    acc[i][j] = fmaf(a[i], bb[j], acc[i][j]);
        }
        __syncthreads();
    }
    #pragma unroll
    for (int i = 0; i < 8; ++i) {
        const int o = obase + to * 8 + i;
        if (o < COUT) {
            #pragma unroll
            for (int j = 0; j < 8; ++j) {
                const int k = kbase + tk + 16 * j;
                if (k < K) Wf[(size_t)o * K + k] = acc[i][j];
            }
        }
    }
}

// ================= reorder: Wb[o][s*CPAD+c] = bf16(Wf[o][c*27+s]) (no BN scale) =================
__global__ __launch_bounds__(256) void reorder_w(const float* __restrict__ Wf,
                                                 unsigned short* __restrict__ Wb,
                                                 int K, int CPAD, int KPAD, int COUT)
{
    const int o = blockIdx.x, tid = threadIdx.x;
    unsigned short* row = Wb + (size_t)o * KPAD;
    for (int i = tid; i < KPAD; i += 256) row[i] = 0;
    __syncthreads();
    if (o < COUT) {
        const float* wr = Wf + (size_t)o * K;
        for (int k = tid; k < K; k += 256) {
            const int c = k / 27, s = k - c * 27;
            row[s * CPAD + c] = f2bf(wr[k]);
        }
    }
}

// ================= implicit-GEMM MFMA conv + clamp(1+x,0) + pool(1,2,2), pre-BN fp32 out =================
// Input: bf16 halo NDHWC [B][18][HI+2][WI+2][CPAD]. Weights: bf16 [*][KPAD], k = s*CPAD+c.
// Block: 256 thr / 4 waves; tile 64(M) x NBLK(N); K-step 32. Gather = table lookup + 16B copy.
template<int CPAD, int COUT, int KPAD, int HI, int WI, int HP, int WP, int NBLK, int SPLIT>
__global__ __launch_bounds__(256) void conv_mfma(
    const unsigned short* __restrict__ in, const unsigned short* __restrict__ Wb,
    float* __restrict__ outf, float* __restrict__ part)
{
    constexpr int NT = NBLK / 16;
    constexpr int HI2 = HI + 2, WI2 = WI + 2;
    constexpr bool C8 = (CPAD % 8 == 0);
    constexpr int TABN = C8 ? KPAD / 8 : KPAD / 4;
    constexpr int NSTEP = KPAD / 32 / SPLIT;
    constexpr int MTOT = 2 * 16 * HP * WP * 4;

    __shared__ __align__(16) unsigned short As[64 * 40];
    __shared__ __align__(16) unsigned short Bs[NBLK * 40];
    __shared__ int tab[TABN];

    const int tid = threadIdx.x;
    const int lane = tid & 63;
    const int wv = tid >> 6;
    const int blk_m = blockIdx.x;
    const int oc0 = blockIdx.y * NBLK;
    const int kc = (SPLIT > 1) ? blockIdx.z : 0;

    // gather offset table (k-group -> element offset in halo layout, or -1 for k-pad)
    for (int i = tid; i < TABN; i += 256) {
        const int k = i * (C8 ? 8 : 4);
        const int s = k / CPAD, c = k % CPAD;
        tab[i] = (s < 27) ? ((((s / 9) * HI2 + (s % 9) / 3) * WI2 + (s % 3)) * CPAD + c) : -1;
    }

    // per-thread gather row
    const int m_l = tid & 63;
    const int oct = tid >> 6;
    const int m_g = blk_m * 64 + m_l;
    const int pooled = m_g >> 2, sub = m_g & 3;
    const int pw_g = pooled % WP;
    const int ph_g = (pooled / WP) % HP;
    const int d_g  = (pooled / (WP * HP)) & 15;
    const int b_g  = pooled / (WP * HP * 16);
    const int h_g = 2 * ph_g + (sub >> 1);
    const int w_g = 2 * pw_g + (sub & 1);
    const size_t base_m = ((((size_t)b_g * 18 + d_g) * HI2 + h_g) * WI2 + w_g) * CPAD;

    f32x4 acc[NT];
    #pragma unroll
    for (int i = 0; i < NT; ++i) acc[i] = (f32x4){0.f, 0.f, 0.f, 0.f};

    const int k_begin = kc * NSTEP * 32;
    __syncthreads();

    for (int s = 0; s < NSTEP; ++s) {
        const int k0 = k_begin + s * 32;
        if constexpr (C8) {
            const int off = tab[(k0 >> 3) + oct];
            sh8 av = (sh8){0, 0, 0, 0, 0, 0, 0, 0};
            if (off >= 0) av = *(const sh8*)(in + base_m + off);
            *(sh8*)&As[m_l * 40 + oct * 8] = av;
        } else {
            #pragma unroll
            for (int hh = 0; hh < 2; ++hh) {
                const int off = tab[(k0 >> 2) + oct * 2 + hh];
                sh4 av = (sh4){0, 0, 0, 0};
                if (off >= 0) av = *(const sh4*)(in + base_m + off);
                *(sh4*)&As[m_l * 40 + oct * 8 + hh * 4] = av;
            }
        }
        for (int i = tid; i < NBLK * 4; i += 256) {
            const int row = i >> 2, cc = i & 3;
            *(sh8*)&Bs[row * 40 + cc * 8] =
                *(const sh8*)&Wb[(size_t)(oc0 + row) * KPAD + k0 + cc * 8];
        }
        __syncthreads();
        const sh8 af = *(const sh8*)&As[(wv * 16 + (lane & 15)) * 40 + (lane >> 4) * 8];
        #pragma unroll
        for (int nt = 0; nt < NT; ++nt) {
            const sh8 bf = *(const sh8*)&Bs[(nt * 16 + (lane & 15)) * 40 + (lane >> 4) * 8];
            acc[nt] = __builtin_amdgcn_mfma_f32_16x16x32_bf16(af, bf, acc[nt], 0, 0, 0);
        }
        __syncthreads();
    }

    const int q = lane >> 4;
    const int nloc = lane & 15;
    if (SPLIT == 1) {
        // each lane quad holds one pooled group (4 prepool values) in its 4 regs
        const int pooled_o = blk_m * 16 + wv * 4 + q;
        #pragma unroll
        for (int nt = 0; nt < NT; ++nt) {
            const int oc = oc0 + nt * 16 + nloc;
            if (oc < COUT) {
                float mx = fmaxf(1.f + acc[nt][0], 0.f);
                mx = fmaxf(mx, fmaxf(1.f + acc[nt][1], 0.f));
                mx = fmaxf(mx, fmaxf(1.f + acc[nt][2], 0.f));
                mx = fmaxf(mx, fmaxf(1.f + acc[nt][3], 0.f));
                outf[(size_t)pooled_o * COUT + oc] = mx;  // pre-BN flat
            }
        }
    } else {
        #pragma unroll
        for (int nt = 0; nt < NT; ++nt) {
            const int oc = oc0 + nt * 16 + nloc;
            #pragma unroll
            for (int r = 0; r < 4; ++r) {
                const int mm = blk_m * 64 + wv * 16 + q * 4 + r;
                part[((size_t)kc * MTOT + mm) * COUT + oc] = acc[nt][r];
            }
        }
    }
}

// ================= split-K reduce + clamp + pool -> pre-BN flat fp32 =================
template<int COUT, int HP, int WP, int SPLIT>
__global__ __launch_bounds__(256) void pool_epi(const float* __restrict__ part,
                                                float* __restrict__ outf)
{
    constexpr int PO = 2 * 16 * HP * WP;
    constexpr int M = PO * 4;
    const int idx = blockIdx.x * 256 + threadIdx.x;
    if (idx >= PO * COUT) return;
    const int oc = idx % COUT;
    const int p = idx / COUT;
    float v[4] = {0.f, 0.f, 0.f, 0.f};
    for (int s = 0; s < SPLIT; ++s)
        #pragma unroll
        for (int r = 0; r < 4; ++r)
            v[r] += part[((size_t)s * M + p * 4 + r) * COUT + oc];
    float mx = fmaxf(1.f + v[0], 0.f);
    mx = fmaxf(mx, fmaxf(1.f + v[1], 0.f));
    mx = fmaxf(mx, fmaxf(1.f + v[2], 0.f));
    mx = fmaxf(mx, fmaxf(1.f + v[3], 0.f));
    outf[(size_t)p * COUT + oc] = mx;
}

// ================= BN stats over flat pre-BN fp32 [P][C] =================
template<int C>
__global__ __launch_bounds__(256) void bn_flat_partial(const float* __restrict__ act,
                                                       float* __restrict__ partial,
                                                       int total)
{
    __shared__ float bs[2 * C];
    const int tid = threadIdx.x;
    for (int i = tid; i < 2 * C; i += 256) bs[i] = 0.f;
    __syncthreads();
    const int start = blockIdx.x * 16384;
    const int end = (start + 16384 < total) ? start + 16384 : total;
    for (int i = start + tid; i < end; i += 256) {
        const float v = act[i];
        const int c = i % C;
        atomicAdd(&bs[c], v);
        atomicAdd(&bs[C + c], v * v);
    }
    __syncthreads();
    for (int i = tid; i < 2 * C; i += 256)
        partial[(size_t)blockIdx.x * 2 * C + i] = bs[i];
}

__global__ __launch_bounds__(256) void bn_reduce(const float* __restrict__ partial,
                                                 const float* __restrict__ gamma,
                                                 const float* __restrict__ beta,
                                                 float* __restrict__ st,
                                                 int R, int C, float inv_n)
{
    const int c = blockIdx.x, tid = threadIdx.x;
    float s = 0.f, q = 0.f;
    for (int r = tid; r < R; r += 256) {
        s += partial[(size_t)r * 2 * C + c];
        q += partial[(size_t)r * 2 * C + C + c];
    }
    __shared__ float rs[256], rq[256];
    rs[tid] = s; rq[tid] = q;
    __syncthreads();
    for (int off = 128; off > 0; off >>= 1) {
        if (tid < off) { rs[tid] += rs[tid + off]; rq[tid] += rq[tid + off]; }
        __syncthreads();
    }
    if (tid == 0) {
        const float mean = rs[0] * inv_n;
        const float var  = rq[0] * inv_n - mean * mean;
        const float sc   = gamma[c] * rsqrtf(var + EPS_BN);
        st[2 * c]     = sc;
        st[2 * c + 1] = fmaf(-mean, sc, beta[c]);
    }
}

// ================= BN apply: pre-BN fp32 flat -> bf16 halo interior (single rounding) =================
template<int C, int HP, int WP>
__global__ __launch_bounds__(256) void bn_apply_halo(const float* __restrict__ pre,
                                                     const float* __restrict__ st,
                                                     unsigned short* __restrict__ outh)
{
    constexpr int PO = 2 * 16 * HP * WP;
    const int idx = blockIdx.x * 256 + threadIdx.x;
    if (idx >= PO * C) return;
    const int c = idx % C;
    const int p = idx / C;
    const int pw = p % WP;
    const int ph = (p / WP) % HP;
    const int d  = (p / (WP * HP)) & 15;
    const int b  = p / (WP * HP * 16);
    const float v = fmaf(pre[idx], st[2 * c], st[2 * c + 1]);
    outh[((((size_t)b * 18 + d + 1) * (HP + 2) + ph + 1) * (WP + 2) + pw + 1) * C + c] = f2bf(v);
}

// ================= L5: flat pre-BN fp32 + BN -> NCDHW flat fp32 for fc1 =================
__global__ __launch_bounds__(256) void transpose5(const float* __restrict__ out5,
                                                  const float* __restrict__ st,
                                                  float* __restrict__ h)
{
    const int idx = blockIdx.x * 256 + threadIdx.x;
    if (idx >= 110592) return;
    const int c = idx % 384;
    const int p = idx / 384;
    const int b = p / 144;
    const int sp = p % 144;
    h[(size_t)b * 55296 + c * 144 + sp] = fmaf(out5[idx], st[2 * c], st[2 * c + 1]);
}

// ================= fc layers =================
__global__ __launch_bounds__(256) void fc1_k(const float* __restrict__ h,
                                             const float* __restrict__ w1,
                                             const float* __restrict__ b1,
                                             float* __restrict__ hout)
{
    __shared__ float r0[256];
    __shared__ float r1[256];
    const int j = blockIdx.x, tid = threadIdx.x;
    const float* wr = w1 + (size_t)j * 55296;
    float a0 = 0.f, a1 = 0.f;
    for (int k = tid * 4; k < 55296; k += 1024) {
        const float4 w = *(const float4*)(wr + k);
        const float4 u = *(const float4*)(h + k);
        const float4 v = *(const float4*)(h + 55296 + k);
        a0 += w.x * u.x + w.y * u.y + w.z * u.z + w.w * u.w;
        a1 += w.x * v.x + w.y * v.y + w.z * v.z + w.w * v.w;
    }
    r0[tid] = a0; r1[tid] = a1;
    __syncthreads();
    for (int off = 128; off > 0; off >>= 1) {
        if (tid < off) { r0[tid] += r0[tid + off]; r1[tid] += r1[tid + off]; }
        __syncthreads();
    }
    if (tid == 0) {
        hout[j]       = fmaxf(r0[0] + b1[j], 0.f);
        hout[512 + j] = fmaxf(r1[0] + b1[j], 0.f);
    }
}

__global__ __launch_bounds__(256) void fc23_k(const float* __restrict__ h1,
                                              const float* __restrict__ w2,
                                              const float* __restrict__ b2,
                                              const float* __restrict__ w3,
                                              const float* __restrict__ b3,
                                              float* __restrict__ out)
{
    __shared__ float h1s[1024];
    __shared__ float h2[512];
    const int tid = threadIdx.x;
    for (int i = tid; i < 1024; i += 256) h1s[i] = h1[i];
    __syncthreads();
    {
        const float* wr = w2 + (size_t)tid * 512;
        #pragma unroll
        for (int b = 0; b < 2; ++b) {
            float a = 0.f;
            const float* hh = h1s + b * 512;
            for (int k = 0; k < 512; ++k) a = fmaf(wr[k], hh[k], a);
            h2[b * 256 + tid] = fmaxf(a + b2[tid], 0.f);
        }
    }
    __syncthreads();
    if (tid < 101) {
        const float* wr = w3 + (size_t)tid * 256;
        #pragma unroll
        for (int b = 0; b < 2; ++b) {
            float a = 0.f;
            const float* hh = h2 + b * 256;
            for (int k = 0; k < 256; ++k) a = fmaf(wr[k], hh[k], a);
            out[b * 101 + tid] = a + b3[tid];
        }
    }
}

// ================= host =================
extern "C" void kernel_launch(void* const* d_in, const int* in_sizes, int n_in,
                              void* d_out, int out_size, void* d_ws, size_t ws_size,
                              hipStream_t stream)
{
    const float* x  = (const float*)d_in[0];
    const float* p[5], *al[5], *g[5], *q[5];
    for (int i = 0; i < 5; ++i) {
        p[i]  = (const float*)d_in[1 + 4 * i];
        al[i] = (const float*)d_in[2 + 4 * i];
        g[i]  = (const float*)d_in[3 + 4 * i];
        q[i]  = (const float*)d_in[4 + 4 * i];
    }
    const float* w1 = (const float*)d_in[21];
    const float* b1 = (const float*)d_in[22];
    const float* w2 = (const float*)d_in[23];
    const float* b2 = (const float*)d_in[24];
    const float* w3 = (const float*)d_in[25];
    const float* b3 = (const float*)d_in[26];

    float* ws = nullptr;
    hipGetSymbolAddress((void**)&ws, HIP_SYMBOL(g_ws));
    unsigned short* act = nullptr;
    hipGetSymbolAddress((void**)&act, HIP_SYMBOL(g_act));
    unsigned short* wb = nullptr;
    hipGetSymbolAddress((void**)&wb, HIP_SYMBOL(g_wb));

    float* Wf[5];
    for (int i = 0; i < 5; ++i) Wf[i] = ws + WF_OFF[i];
    float* part = ws + PART_OFF;
    float* pre  = ws + PRE_OFF;
    float* out5 = ws + OUT5_OFF;
    float* h    = ws + H_OFF;
    float* st   = ws + ST_OFF;
    float* bnp  = ws + BNP_OFF;
    float* h1   = ws + H1_OFF;

    unsigned short* xin = act + XIN_OFF;
    unsigned short* a1  = act + A1_OFF;
    unsigned short* a2  = act + A2_OFF;
    unsigned short* a3  = act + A3_OFF;
    unsigned short* a4  = act + A4_OFF;

    // zero bf16 activation arena (halos + channel pad must be 0)
    zero16<<<(AR_TOT * 2 / 16 + 255) / 256, 256, 0, stream>>>((int4*)act, (int)(AR_TOT * 2 / 16));
    convert_input<<<(2 * 18 * 114 * 114 * 4 + 255) / 256, 256, 0, stream>>>(x, xin);

    static const int KF[5] = {81, 648, 1296, 2592, 5184};
    static const int CO[5] = {24, 48, 96, 192, 384};
    static const int CP[5] = {4, 24, 48, 96, 192};
    static const int KP[5] = {128, 672, 1312, 2592, 5184};
    static const int NPAD[5] = {32, 48, 96, 192, 384};
    for (int i = 0; i < 5; ++i) {
        dim3 gb((KF[i] + 127) / 128, (CO[i] + 127) / 128);
        fuse_w<<<gb, 256, 0, stream>>>(p[i], al[i], Wf[i], KF[i], CO[i]);
        reorder_w<<<NPAD[i], 256, 0, stream>>>(Wf[i], wb + WB_OFF[i], KF[i], CP[i], KP[i], CO[i]);
    }

    // ---- L1: xin -> pre (2*16*56*56 x 24) ----
    conv_mfma<4, 24, 128, 112, 112, 56, 56, 32, 1>
        <<<dim3(6272, 1), 256, 0, stream>>>(xin, wb + WB_OFF[0], pre, nullptr);
    bn_flat_partial<24><<<147, 256, 0, stream>>>(pre, bnp, 2408448);
    bn_reduce<<<24, 256, 0, stream>>>(bnp, g[0], q[0], st, 147, 24, 1.f / 100352.f);
    bn_apply_halo<24, 56, 56><<<9408, 256, 0, stream>>>(pre, st, a1);

    // ---- L2: a1 -> pre (2*16*28*28 x 48) ----
    conv_mfma<24, 48, 672, 56, 56, 28, 28, 48, 1>
        <<<dim3(1568, 1), 256, 0, stream>>>(a1, wb + WB_OFF[1], pre, nullptr);
    bn_flat_partial<48><<<74, 256, 0, stream>>>(pre, bnp, 1204224);
    bn_reduce<<<48, 256, 0, stream>>>(bnp, g[1], q[1], st, 74, 48, 1.f / 25088.f);
    bn_apply_halo<48, 28, 28><<<4704, 256, 0, stream>>>(pre, st, a2);

    // ---- L3: a2 -> pre (2*16*14*14 x 96) ----
    conv_mfma<48, 96, 1312, 28, 28, 14, 14, 48, 1>
        <<<dim3(392, 2), 256, 0, stream>>>(a2, wb + WB_OFF[2], pre, nullptr);
    bn_flat_partial<96><<<37, 256, 0, stream>>>(pre, bnp, 602112);
    bn_reduce<<<96, 256, 0, stream>>>(bnp, g[2], q[2], st, 37, 96, 1.f / 6272.f);
    bn_apply_halo<96, 14, 14><<<2352, 256, 0, stream>>>(pre, st, a3);

    // ---- L4: a3 -> pre (2*16*7*7 x 192), split-K 3 ----
    conv_mfma<96, 192, 2592, 14, 14, 7, 7, 64, 3>
        <<<dim3(98, 3, 3), 256, 0, stream>>>(a3, wb + WB_OFF[3], nullptr, part);
    pool_epi<192, 7, 7, 3><<<1176, 256, 0, stream>>>(part, pre);
    bn_flat_partial<192><<<19, 256, 0, stream>>>(pre, bnp, 301056);
    bn_reduce<<<192, 256, 0, stream>>>(bnp, g[3], q[3], st, 19, 192, 1.f / 1568.f);
    bn_apply_halo<192, 7, 7><<<1176, 256, 0, stream>>>(pre, st, a4);

    // ---- L5: a4 -> out5 (2*16*3*3 x 384), split-K 6 ----
    conv_mfma<192, 384, 5184, 7, 7, 3, 3, 64, 6>
        <<<dim3(18, 6, 6), 256, 0, stream>>>(a4, wb + WB_OFF[4], nullptr, part);
    pool_epi<384, 3, 3, 6><<<432, 256, 0, stream>>>(part, out5);
    bn_flat_partial<384><<<7, 256, 0, stream>>>(out5, bnp, 110592);
    bn_reduce<<<384, 256, 0, stream>>>(bnp, g[4], q[4], st, 7, 384, 1.f / 288.f);

    // ---- head ----
    transpose5<<<(110592 + 255) / 256, 256, 0, stream>>>(out5, st, h);
    fc1_k<<<512, 256, 0, stream>>>(h, w1, b1, h1);
    fc23_k<<<1, 256, 0, stream>>>(h1, w2, b2, w3, b3, (float*)d_out);
}

// Round 6
// 734.319 us; speedup vs baseline: 2.9341x; 1.8235x over previous
//
#include <hip/hip_runtime.h>

#define EPS_BN 1e-5f

typedef __attribute__((ext_vector_type(8))) short sh8;
typedef __attribute__((ext_vector_type(4))) short sh4;
typedef __attribute__((ext_vector_type(4))) float f32x4;

// ================= fp32 workspace arena =================
static const size_t WF_OFF[5] = {0, 1944, 33048, 157464, 655128};  // fused fp32 weights [COUT][K]
static const size_t PART_OFF = 2645784;   // split-K partials (max 3*6272*192 = 3612672)
static const size_t PRE_OFF  = 6258456;   // pre-BN flat conv output (max 2408448)
static const size_t OUT5_OFF = 8666904;   // 110592 L5 pre-BN flat
static const size_t H_OFF    = 8777496;   // 110592 fc1 input (NCDHW flat)
static const size_t ST_OFF   = 8888088;   // 768 per-channel scale/shift
static const size_t BNP_OFF  = 8888856;   // 8192 bn partials
static const size_t H1_OFF   = 8897048;   // 1024 fc1 output
static const size_t WS_TOT   = 8898072;   // ~35.6 MB
__device__ __align__(256) float g_ws[WS_TOT];

// bf16 activation arena (halo-padded NDHWC), zeroed each launch
static const size_t XIN_OFF = 0;         // [2][18][114][114][4]  = 1871424
static const size_t A1_OFF  = 1871424;   // [2][18][58][58][24]   = 2905344
static const size_t A2_OFF  = 4776768;   // [2][18][30][30][48]   = 1555200
static const size_t A3_OFF  = 6331968;   // [2][18][16][16][96]   = 884736
static const size_t A4_OFF  = 7216704;   // [2][18][9][9][192]    = 559872
static const size_t AR_TOT  = 7776576;
__device__ __align__(256) unsigned short g_act[AR_TOT];

// bf16 conv weights [NPAD][KPAD], k-order = s*CPAD+c
static const size_t WB_OFF[5] = {0, 4096, 36352, 162304, 659968};
__device__ __align__(256) unsigned short g_wb[2650624];

__device__ inline unsigned short f2bf(float v) {
    unsigned u = __float_as_uint(v);
    return (unsigned short)((u + 0x7fffu + ((u >> 16) & 1u)) >> 16);
}

// ================= zero arena =================
__global__ __launch_bounds__(256) void zero16(int4* __restrict__ p, int n) {
    const int i = blockIdx.x * 256 + threadIdx.x;
    if (i < n) p[i] = make_int4(0, 0, 0, 0);
}

// ================= input: NCDHW fp32 -> halo NDHWC bf16 (Cpad=4) =================
__global__ __launch_bounds__(256) void convert_input(const float* __restrict__ x,
                                                     unsigned short* __restrict__ xp)
{
    const int i = blockIdx.x * 256 + threadIdx.x;
    if (i >= 2 * 18 * 114 * 114 * 4) return;
    const int c = i & 3;
    int t = i >> 2;
    const int xx = t % 114; t /= 114;
    const int yy = t % 114; t /= 114;
    const int zz = t % 18;
    const int b  = t / 18;
    float v = 0.f;
    if (c < 3 && (unsigned)(zz - 1) < 16u && (unsigned)(yy - 1) < 112u && (unsigned)(xx - 1) < 112u)
        v = x[(((size_t)b * 3 + c) * 16 + (zz - 1)) * 12544 + (yy - 1) * 112 + (xx - 1)];
    xp[i] = f2bf(v);
}

// ================= fuse ALL layers in one dispatch =================
// Wf[o][k] = sum_p proj[p][k] * alpha[p][o]; 64x64 tiles, 4x4/thread, P-chunk 16.
struct FuseArgs {
    const float* proj[5];
    const float* alpha[5];
    float* Wf[5];
    int K[5];
    int CO[5];
    int NT[5];
    int start[6];
};

__global__ __launch_bounds__(256) void fuse_all(FuseArgs a)
{
    __shared__ __align__(16) float sa[16][64];  // [p][o]
    __shared__ __align__(16) float sp[16][64];  // [p][k]

    int l = 0;
    {
        const int bx = blockIdx.x;
        while (l < 4 && bx >= a.start[l + 1]) ++l;
    }
    const int idx = blockIdx.x - a.start[l];
    const int NT = a.NT[l];
    const int obase = (idx / NT) * 64;
    const int kbase = (idx % NT) * 64;
    const int K = a.K[l], CO = a.CO[l];
    const float* __restrict__ proj  = a.proj[l];
    const float* __restrict__ alpha = a.alpha[l];
    float* __restrict__ Wf = a.Wf[l];

    const int tid = threadIdx.x;
    const int tk = tid & 15, to = tid >> 4;

    // staging coords (fixed per thread)
    const int pp  = tid >> 4;
    const int col = (tid & 15) * 4;
    const int o_st = obase + col;
    const int k_st = kbase + col;
    const bool a_ok  = (o_st < CO);                         // CO,o_st mult of 4
    const bool p_vec = ((K & 3) == 0) && (k_st + 4 <= K);

    float acc[4][4];
    #pragma unroll
    for (int i = 0; i < 4; ++i)
        #pragma unroll
        for (int j = 0; j < 4; ++j) acc[i][j] = 0.f;

    for (int p0 = 0; p0 < 512; p0 += 16) {
        const float* ap  = alpha + (size_t)(p0 + pp) * CO;
        const float* prp = proj  + (size_t)(p0 + pp) * K;
        float4 va = make_float4(0.f, 0.f, 0.f, 0.f);
        float4 vp = make_float4(0.f, 0.f, 0.f, 0.f);
        if (a_ok) va = *(const float4*)(ap + o_st);
        if (p_vec) {
            vp = *(const float4*)(prp + k_st);
        } else {
            float t4[4];
            #pragma unroll
            for (int j = 0; j < 4; ++j)
                t4[j] = (k_st + j < K) ? prp[k_st + j] : 0.f;
            vp = make_float4(t4[0], t4[1], t4[2], t4[3]);
        }
        *(float4*)&sa[pp][col] = va;
        *(float4*)&sp[pp][col] = vp;
        __syncthreads();
        #pragma unroll
        for (int p = 0; p < 16; ++p) {
            const float4 a4 = *(const float4*)&sa[p][to * 4];
            const float4 b4 = *(const float4*)&sp[p][tk * 4];
            const float aa[4] = {a4.x, a4.y, a4.z, a4.w};
            const float bb[4] = {b4.x, b4.y, b4.z, b4.w};
            #pragma unroll
            for (int i = 0; i < 4; ++i)
                #pragma unroll
                for (int j = 0; j < 4; ++j)
                    acc[i][j] = fmaf(aa[i], bb[j], acc[i][j]);
        }
        __syncthreads();
    }

    #pragma unroll
    for (int i = 0; i < 4; ++i) {
        const int o = obase + to * 4 + i;
        if (o < CO) {
            #pragma unroll
            for (int j = 0; j < 4; ++j) {
                const int kk = kbase + tk * 4 + j;
                if (kk < K) Wf[(size_t)o * K + kk] = acc[i][j];
            }
        }
    }
}

// ================= reorder ALL layers in one dispatch =================
// Wb[o][s*CPAD+c] = bf16(Wf[o][c*27+s]), zero-padded rows/cols
struct ReordArgs {
    const float* Wf[5];
    unsigned short* Wb[5];
    int K[5], CPAD[5], KPAD[5], CO[5];
    int start[6];
};

__global__ __launch_bounds__(256) void reorder_all(ReordArgs a)
{
    int l = 0;
    {
        const int bx = blockIdx.x;
        while (l < 4 && bx >= a.start[l + 1]) ++l;
    }
    const int o = blockIdx.x - a.start[l];
    const int K = a.K[l], CPAD = a.CPAD[l], KPAD = a.KPAD[l], CO = a.CO[l];
    const int tid = threadIdx.x;
    unsigned short* row = a.Wb[l] + (size_t)o * KPAD;
    for (int i = tid; i < KPAD; i += 256) row[i] = 0;
    __syncthreads();
    if (o < CO) {
        const float* wr = a.Wf[l] + (size_t)o * K;
        for (int k = tid; k < K; k += 256) {
            const int c = k / 27, s = k - c * 27;
            row[s * CPAD + c] = f2bf(wr[k]);
        }
    }
}

// ================= implicit-GEMM MFMA conv + clamp(1+x,0) + pool(1,2,2), pre-BN fp32 out =================
template<int CPAD, int COUT, int KPAD, int HI, int WI, int HP, int WP, int NBLK, int SPLIT>
__global__ __launch_bounds__(256) void conv_mfma(
    const unsigned short* __restrict__ in, const unsigned short* __restrict__ Wb,
    float* __restrict__ outf, float* __restrict__ part)
{
    constexpr int NT = NBLK / 16;
    constexpr int HI2 = HI + 2, WI2 = WI + 2;
    constexpr bool C8 = (CPAD % 8 == 0);
    constexpr int TABN = C8 ? KPAD / 8 : KPAD / 4;
    constexpr int NSTEP = KPAD / 32 / SPLIT;
    constexpr int MTOT = 2 * 16 * HP * WP * 4;

    __shared__ __align__(16) unsigned short As[64 * 40];
    __shared__ __align__(16) unsigned short Bs[NBLK * 40];
    __shared__ int tab[TABN];

    const int tid = threadIdx.x;
    const int lane = tid & 63;
    const int wv = tid >> 6;
    const int blk_m = blockIdx.x;
    const int oc0 = blockIdx.y * NBLK;
    const int kc = (SPLIT > 1) ? blockIdx.z : 0;

    for (int i = tid; i < TABN; i += 256) {
        const int k = i * (C8 ? 8 : 4);
        const int s = k / CPAD, c = k % CPAD;
        tab[i] = (s < 27) ? ((((s / 9) * HI2 + (s % 9) / 3) * WI2 + (s % 3)) * CPAD + c) : -1;
    }

    const int m_l = tid & 63;
    const int oct = tid >> 6;
    const int m_g = blk_m * 64 + m_l;
    const int pooled = m_g >> 2, sub = m_g & 3;
    const int pw_g = pooled % WP;
    const int ph_g = (pooled / WP) % HP;
    const int d_g  = (pooled / (WP * HP)) & 15;
    const int b_g  = pooled / (WP * HP * 16);
    const int h_g = 2 * ph_g + (sub >> 1);
    const int w_g = 2 * pw_g + (sub & 1);
    const size_t base_m = ((((size_t)b_g * 18 + d_g) * HI2 + h_g) * WI2 + w_g) * CPAD;

    f32x4 acc[NT];
    #pragma unroll
    for (int i = 0; i < NT; ++i) acc[i] = (f32x4){0.f, 0.f, 0.f, 0.f};

    const int k_begin = kc * NSTEP * 32;
    __syncthreads();

    for (int s = 0; s < NSTEP; ++s) {
        const int k0 = k_begin + s * 32;
        if constexpr (C8) {
            const int off = tab[(k0 >> 3) + oct];
            sh8 av = (sh8){0, 0, 0, 0, 0, 0, 0, 0};
            if (off >= 0) av = *(const sh8*)(in + base_m + off);
            *(sh8*)&As[m_l * 40 + oct * 8] = av;
        } else {
            #pragma unroll
            for (int hh = 0; hh < 2; ++hh) {
                const int off = tab[(k0 >> 2) + oct * 2 + hh];
                sh4 av = (sh4){0, 0, 0, 0};
                if (off >= 0) av = *(const sh4*)(in + base_m + off);
                *(sh4*)&As[m_l * 40 + oct * 8 + hh * 4] = av;
            }
        }
        for (int i = tid; i < NBLK * 4; i += 256) {
            const int row = i >> 2, cc = i & 3;
            *(sh8*)&Bs[row * 40 + cc * 8] =
                *(const sh8*)&Wb[(size_t)(oc0 + row) * KPAD + k0 + cc * 8];
        }
        __syncthreads();
        const sh8 af = *(const sh8*)&As[(wv * 16 + (lane & 15)) * 40 + (lane >> 4) * 8];
        #pragma unroll
        for (int nt = 0; nt < NT; ++nt) {
            const sh8 bf = *(const sh8*)&Bs[(nt * 16 + (lane & 15)) * 40 + (lane >> 4) * 8];
            acc[nt] = __builtin_amdgcn_mfma_f32_16x16x32_bf16(af, bf, acc[nt], 0, 0, 0);
        }
        __syncthreads();
    }

    const int q = lane >> 4;
    const int nloc = lane & 15;
    if (SPLIT == 1) {
        const int pooled_o = blk_m * 16 + wv * 4 + q;
        #pragma unroll
        for (int nt = 0; nt < NT; ++nt) {
            const int oc = oc0 + nt * 16 + nloc;
            if (oc < COUT) {
                float mx = fmaxf(1.f + acc[nt][0], 0.f);
                mx = fmaxf(mx, fmaxf(1.f + acc[nt][1], 0.f));
                mx = fmaxf(mx, fmaxf(1.f + acc[nt][2], 0.f));
                mx = fmaxf(mx, fmaxf(1.f + acc[nt][3], 0.f));
                outf[(size_t)pooled_o * COUT + oc] = mx;
            }
        }
    } else {
        #pragma unroll
        for (int nt = 0; nt < NT; ++nt) {
            const int oc = oc0 + nt * 16 + nloc;
            #pragma unroll
            for (int r = 0; r < 4; ++r) {
                const int mm = blk_m * 64 + wv * 16 + q * 4 + r;
                part[((size_t)kc * MTOT + mm) * COUT + oc] = acc[nt][r];
            }
        }
    }
}

// ================= split-K reduce + clamp + pool -> pre-BN flat fp32 =================
template<int COUT, int HP, int WP, int SPLIT>
__global__ __launch_bounds__(256) void pool_epi(const float* __restrict__ part,
                                                float* __restrict__ outf)
{
    constexpr int PO = 2 * 16 * HP * WP;
    constexpr int M = PO * 4;
    const int idx = blockIdx.x * 256 + threadIdx.x;
    if (idx >= PO * COUT) return;
    const int oc = idx % COUT;
    const int p = idx / COUT;
    float v[4] = {0.f, 0.f, 0.f, 0.f};
    for (int s = 0; s < SPLIT; ++s)
        #pragma unroll
        for (int r = 0; r < 4; ++r)
            v[r] += part[((size_t)s * M + p * 4 + r) * COUT + oc];
    float mx = fmaxf(1.f + v[0], 0.f);
    mx = fmaxf(mx, fmaxf(1.f + v[1], 0.f));
    mx = fmaxf(mx, fmaxf(1.f + v[2], 0.f));
    mx = fmaxf(mx, fmaxf(1.f + v[3], 0.f));
    outf[(size_t)p * COUT + oc] = mx;
}

// ================= BN stats over flat pre-BN fp32 [P][C] =================
template<int C>
__global__ __launch_bounds__(256) void bn_flat_partial(const float* __restrict__ act,
                                                       float* __restrict__ partial,
                                                       int total)
{
    __shared__ float bs[2 * C];
    const int tid = threadIdx.x;
    for (int i = tid; i < 2 * C; i += 256) bs[i] = 0.f;
    __syncthreads();
    const int start = blockIdx.x * 16384;
    const int end = (start + 16384 < total) ? start + 16384 : total;
    for (int i = start + tid; i < end; i += 256) {
        const float v = act[i];
        const int c = i % C;
        atomicAdd(&bs[c], v);
        atomicAdd(&bs[C + c], v * v);
    }
    __syncthreads();
    for (int i = tid; i < 2 * C; i += 256)
        partial[(size_t)blockIdx.x * 2 * C + i] = bs[i];
}

__global__ __launch_bounds__(256) void bn_reduce(const float* __restrict__ partial,
                                                 const float* __restrict__ gamma,
                                                 const float* __restrict__ beta,
                                                 float* __restrict__ st,
                                                 int R, int C, float inv_n)
{
    const int c = blockIdx.x, tid = threadIdx.x;
    float s = 0.f, q = 0.f;
    for (int r = tid; r < R; r += 256) {
        s += partial[(size_t)r * 2 * C + c];
        q += partial[(size_t)r * 2 * C + C + c];
    }
    __shared__ float rs[256], rq[256];
    rs[tid] = s; rq[tid] = q;
    __syncthreads();
    for (int off = 128; off > 0; off >>= 1) {
        if (tid < off) { rs[tid] += rs[tid + off]; rq[tid] += rq[tid + off]; }
        __syncthreads();
    }
    if (tid == 0) {
        const float mean = rs[0] * inv_n;
        const float var  = rq[0] * inv_n - mean * mean;
        const float sc   = gamma[c] * rsqrtf(var + EPS_BN);
        st[2 * c]     = sc;
        st[2 * c + 1] = fmaf(-mean, sc, beta[c]);
    }
}

// ================= BN apply: pre-BN fp32 flat -> bf16 halo interior =================
template<int C, int HP, int WP>
__global__ __launch_bounds__(256) void bn_apply_halo(const float* __restrict__ pre,
                                                     const float* __restrict__ st,
                                                     unsigned short* __restrict__ outh)
{
    constexpr int PO = 2 * 16 * HP * WP;
    const int idx = blockIdx.x * 256 + threadIdx.x;
    if (idx >= PO * C) return;
    const int c = idx % C;
    const int p = idx / C;
    const int pw = p % WP;
    const int ph = (p / WP) % HP;
    const int d  = (p / (WP * HP)) & 15;
    const int b  = p / (WP * HP * 16);
    const float v = fmaf(pre[idx], st[2 * c], st[2 * c + 1]);
    outh[((((size_t)b * 18 + d + 1) * (HP + 2) + ph + 1) * (WP + 2) + pw + 1) * C + c] = f2bf(v);
}

// ================= L5: flat pre-BN fp32 + BN -> NCDHW flat fp32 for fc1 =================
__global__ __launch_bounds__(256) void transpose5(const float* __restrict__ out5,
                                                  const float* __restrict__ st,
                                                  float* __restrict__ h)
{
    const int idx = blockIdx.x * 256 + threadIdx.x;
    if (idx >= 110592) return;
    const int c = idx % 384;
    const int p = idx / 384;
    const int b = p / 144;
    const int sp = p % 144;
    h[(size_t)b * 55296 + c * 144 + sp] = fmaf(out5[idx], st[2 * c], st[2 * c + 1]);
}

// ================= fc layers =================
__global__ __launch_bounds__(256) void fc1_k(const float* __restrict__ h,
                                             const float* __restrict__ w1,
                                             const float* __restrict__ b1,
                                             float* __restrict__ hout)
{
    __shared__ float r0[256];
    __shared__ float r1[256];
    const int j = blockIdx.x, tid = threadIdx.x;
    const float* wr = w1 + (size_t)j * 55296;
    float a0 = 0.f, a1 = 0.f;
    for (int k = tid * 4; k < 55296; k += 1024) {
        const float4 w = *(const float4*)(wr + k);
        const float4 u = *(const float4*)(h + k);
        const float4 v = *(const float4*)(h + 55296 + k);
        a0 += w.x * u.x + w.y * u.y + w.z * u.z + w.w * u.w;
        a1 += w.x * v.x + w.y * v.y + w.z * v.z + w.w * v.w;
    }
    r0[tid] = a0; r1[tid] = a1;
    __syncthreads();
    for (int off = 128; off > 0; off >>= 1) {
        if (tid < off) { r0[tid] += r0[tid + off]; r1[tid] += r1[tid + off]; }
        __syncthreads();
    }
    if (tid == 0) {
        hout[j]       = fmaxf(r0[0] + b1[j], 0.f);
        hout[512 + j] = fmaxf(r1[0] + b1[j], 0.f);
    }
}

__global__ __launch_bounds__(256) void fc23_k(const float* __restrict__ h1,
                                              const float* __restrict__ w2,
                                              const float* __restrict__ b2,
                                              const float* __restrict__ w3,
                                              const float* __restrict__ b3,
                                              float* __restrict__ out)
{
    __shared__ float h1s[1024];
    __shared__ float h2[512];
    const int tid = threadIdx.x;
    for (int i = tid; i < 1024; i += 256) h1s[i] = h1[i];
    __syncthreads();
    {
        const float* wr = w2 + (size_t)tid * 512;
        #pragma unroll
        for (int b = 0; b < 2; ++b) {
            float a = 0.f;
            const float* hh = h1s + b * 512;
            for (int k = 0; k < 512; ++k) a = fmaf(wr[k], hh[k], a);
            h2[b * 256 + tid] = fmaxf(a + b2[tid], 0.f);
        }
    }
    __syncthreads();
    if (tid < 101) {
        const float* wr = w3 + (size_t)tid * 256;
        #pragma unroll
        for (int b = 0; b < 2; ++b) {
            float a = 0.f;
            const float* hh = h2 + b * 256;
            for (int k = 0; k < 256; ++k) a = fmaf(wr[k], hh[k], a);
            out[b * 101 + tid] = a + b3[tid];
        }
    }
}

// ================= host =================
extern "C" void kernel_launch(void* const* d_in, const int* in_sizes, int n_in,
                              void* d_out, int out_size, void* d_ws, size_t ws_size,
                              hipStream_t stream)
{
    const float* x  = (const float*)d_in[0];
    const float* p[5], *al[5], *g[5], *q[5];
    for (int i = 0; i < 5; ++i) {
        p[i]  = (const float*)d_in[1 + 4 * i];
        al[i] = (const float*)d_in[2 + 4 * i];
        g[i]  = (const float*)d_in[3 + 4 * i];
        q[i]  = (const float*)d_in[4 + 4 * i];
    }
    const float* w1 = (const float*)d_in[21];
    const float* b1 = (const float*)d_in[22];
    const float* w2 = (const float*)d_in[23];
    const float* b2 = (const float*)d_in[24];
    const float* w3 = (const float*)d_in[25];
    const float* b3 = (const float*)d_in[26];

    float* ws = nullptr;
    hipGetSymbolAddress((void**)&ws, HIP_SYMBOL(g_ws));
    unsigned short* act = nullptr;
    hipGetSymbolAddress((void**)&act, HIP_SYMBOL(g_act));
    unsigned short* wb = nullptr;
    hipGetSymbolAddress((void**)&wb, HIP_SYMBOL(g_wb));

    float* Wf[5];
    for (int i = 0; i < 5; ++i) Wf[i] = ws + WF_OFF[i];
    float* part = ws + PART_OFF;
    float* pre  = ws + PRE_OFF;
    float* out5 = ws + OUT5_OFF;
    float* h    = ws + H_OFF;
    float* st   = ws + ST_OFF;
    float* bnp  = ws + BNP_OFF;
    float* h1   = ws + H1_OFF;

    unsigned short* xin = act + XIN_OFF;
    unsigned short* a1  = act + A1_OFF;
    unsigned short* a2  = act + A2_OFF;
    unsigned short* a3  = act + A3_OFF;
    unsigned short* a4  = act + A4_OFF;

    // zero bf16 activation arena (halos + channel pad must be 0)
    zero16<<<(AR_TOT * 2 / 16 + 255) / 256, 256, 0, stream>>>((int4*)act, (int)(AR_TOT * 2 / 16));
    convert_input<<<(2 * 18 * 114 * 114 * 4 + 255) / 256, 256, 0, stream>>>(x, xin);

    static const int KF[5] = {81, 648, 1296, 2592, 5184};
    static const int CO[5] = {24, 48, 96, 192, 384};
    static const int CP[5] = {4, 24, 48, 96, 192};
    static const int KP[5] = {128, 672, 1312, 2592, 5184};
    static const int NPAD[5] = {32, 48, 96, 192, 384};

    // one dispatch for all 5 weight-fusion GEMMs
    FuseArgs fa;
    int s0 = 0;
    for (int i = 0; i < 5; ++i) {
        fa.proj[i] = p[i]; fa.alpha[i] = al[i]; fa.Wf[i] = Wf[i];
        fa.K[i] = KF[i]; fa.CO[i] = CO[i];
        const int nt = (KF[i] + 63) / 64;
        const int mt = (CO[i] + 63) / 64;
        fa.NT[i] = nt;
        fa.start[i] = s0;
        s0 += nt * mt;
    }
    fa.start[5] = s0;   // 664
    fuse_all<<<s0, 256, 0, stream>>>(fa);

    // one dispatch for all 5 reorders
    ReordArgs ra;
    int r0 = 0;
    for (int i = 0; i < 5; ++i) {
        ra.Wf[i] = Wf[i]; ra.Wb[i] = wb + WB_OFF[i];
        ra.K[i] = KF[i]; ra.CPAD[i] = CP[i]; ra.KPAD[i] = KP[i]; ra.CO[i] = CO[i];
        ra.start[i] = r0;
        r0 += NPAD[i];
    }
    ra.start[5] = r0;   // 752
    reorder_all<<<r0, 256, 0, stream>>>(ra);

    // ---- L1: xin -> pre (2*16*56*56 x 24) ----
    conv_mfma<4, 24, 128, 112, 112, 56, 56, 32, 1>
        <<<dim3(6272, 1), 256, 0, stream>>>(xin, wb + WB_OFF[0], pre, nullptr);
    bn_flat_partial<24><<<147, 256, 0, stream>>>(pre, bnp, 2408448);
    bn_reduce<<<24, 256, 0, stream>>>(bnp, g[0], q[0], st, 147, 24, 1.f / 100352.f);
    bn_apply_halo<24, 56, 56><<<9408, 256, 0, stream>>>(pre, st, a1);

    // ---- L2: a1 -> pre (2*16*28*28 x 48) ----
    conv_mfma<24, 48, 672, 56, 56, 28, 28, 48, 1>
        <<<dim3(1568, 1), 256, 0, stream>>>(a1, wb + WB_OFF[1], pre, nullptr);
    bn_flat_partial<48><<<74, 256, 0, stream>>>(pre, bnp, 1204224);
    bn_reduce<<<48, 256, 0, stream>>>(bnp, g[1], q[1], st, 74, 48, 1.f / 25088.f);
    bn_apply_halo<48, 28, 28><<<4704, 256, 0, stream>>>(pre, st, a2);

    // ---- L3: a2 -> pre (2*16*14*14 x 96) ----
    conv_mfma<48, 96, 1312, 28, 28, 14, 14, 48, 1>
        <<<dim3(392, 2), 256, 0, stream>>>(a2, wb + WB_OFF[2], pre, nullptr);
    bn_flat_partial<96><<<37, 256, 0, stream>>>(pre, bnp, 602112);
    bn_reduce<<<96, 256, 0, stream>>>(bnp, g[2], q[2], st, 37, 96, 1.f / 6272.f);
    bn_apply_halo<96, 14, 14><<<2352, 256, 0, stream>>>(pre, st, a3);

    // ---- L4: a3 -> pre (2*16*7*7 x 192), split-K 3 ----
    conv_mfma<96, 192, 2592, 14, 14, 7, 7, 64, 3>
        <<<dim3(98, 3, 3), 256, 0, stream>>>(a3, wb + WB_OFF[3], nullptr, part);
    pool_epi<192, 7, 7, 3><<<1176, 256, 0, stream>>>(part, pre);
    bn_flat_partial<192><<<19, 256, 0, stream>>>(pre, bnp, 301056);
    bn_reduce<<<192, 256, 0, stream>>>(bnp, g[3], q[3], st, 19, 192, 1.f / 1568.f);
    bn_apply_halo<192, 7, 7><<<1176, 256, 0, stream>>>(pre, st, a4);

    // ---- L5: a4 -> out5 (2*16*3*3 x 384), split-K 6 ----
    conv_mfma<192, 384, 5184, 7, 7, 3, 3, 64, 6>
        <<<dim3(18, 6, 6), 256, 0, stream>>>(a4, wb + WB_OFF[4], nullptr, part);
    pool_epi<384, 3, 3, 6><<<432, 256, 0, stream>>>(part, out5);
    bn_flat_partial<384><<<7, 256, 0, stream>>>(out5, bnp, 110592);
    bn_reduce<<<384, 256, 0, stream>>>(bnp, g[4], q[4], st, 7, 384, 1.f / 288.f);

    // ---- head ----
    transpose5<<<(110592 + 255) / 256, 256, 0, stream>>>(out5, st, h);
    fc1_k<<<512, 256, 0, stream>>>(h, w1, b1, h1);
    fc23_k<<<1, 256, 0, stream>>>(h1, w2, b2, w3, b3, (float*)d_out);
}

// Round 7
// 541.374 us; speedup vs baseline: 3.9798x; 1.3564x over previous
//
#include <hip/hip_runtime.h>

#define EPS_BN 1e-5f

typedef __attribute__((ext_vector_type(8))) short sh8;
typedef __attribute__((ext_vector_type(4))) short sh4;
typedef __attribute__((ext_vector_type(4))) float f32x4;

// ================= fp32 workspace arena =================
static const size_t WF_OFF[5] = {0, 1944, 33048, 157464, 655128};  // fused fp32 weights [COUT][K]
static const size_t PART_OFF = 2645784;   // split-K partials (max 3*6272*192 = 3612672)
static const size_t PRE_OFF  = 6258456;   // pre-BN flat conv output (max 2408448)
static const size_t OUT5_OFF = 8666904;   // 110592 L5 pre-BN flat
static const size_t H_OFF    = 8777496;   // 110592 fc1 input (NCDHW flat)
static const size_t ST_OFF   = 8888088;   // 768 per-channel scale/shift
static const size_t BNP_OFF  = 8888856;   // 64 rows x 768 = 49152 bn atomic partials
static const size_t H1_OFF   = 8938008;   // 1024 fc1 output
static const size_t WS_TOT   = 8939032;   // ~35.8 MB
__device__ __align__(256) float g_ws[WS_TOT];

// bf16 activation arena (halo-padded NDHWC)
static const size_t XIN_OFF = 0;         // [2][18][114][114][4]  = 1871424 (fully written by convert_input)
static const size_t A1_OFF  = 1871424;   // [2][18][58][58][24]   = 2905344
static const size_t A2_OFF  = 4776768;   // [2][18][30][30][48]   = 1555200
static const size_t A3_OFF  = 6331968;   // [2][18][16][16][96]   = 884736
static const size_t A4_OFF  = 7216704;   // [2][18][9][9][192]    = 559872
static const size_t AR_TOT  = 7776576;
__device__ __align__(256) unsigned short g_act[AR_TOT];

// bf16 conv weights [NPAD][KPAD], k-order = s*CPAD+c
static const size_t WB_OFF[5] = {0, 4096, 36352, 162304, 659968};
__device__ __align__(256) unsigned short g_wb[2650624];

__device__ inline unsigned short f2bf(float v) {
    unsigned u = __float_as_uint(v);
    return (unsigned short)((u + 0x7fffu + ((u >> 16) & 1u)) >> 16);
}

// ================= zero activation arena (A1..A4 only; xin covered by convert) =================
__global__ __launch_bounds__(256) void zero16(int4* __restrict__ p, int n) {
    const int i = blockIdx.x * 256 + threadIdx.x;
    if (i < n) p[i] = make_int4(0, 0, 0, 0);
}

// ================= input: NCDHW fp32 -> halo NDHWC bf16 (Cpad=4); also zero bnp =================
__global__ __launch_bounds__(256) void convert_input(const float* __restrict__ x,
                                                     unsigned short* __restrict__ xp,
                                                     float* __restrict__ bnp)
{
    const int i = blockIdx.x * 256 + threadIdx.x;
    if (i < 49152) bnp[i] = 0.f;
    if (i >= 2 * 18 * 114 * 114 * 4) return;
    const int c = i & 3;
    int t = i >> 2;
    const int xx = t % 114; t /= 114;
    const int yy = t % 114; t /= 114;
    const int zz = t % 18;
    const int b  = t / 18;
    float v = 0.f;
    if (c < 3 && (unsigned)(zz - 1) < 16u && (unsigned)(yy - 1) < 112u && (unsigned)(xx - 1) < 112u)
        v = x[(((size_t)b * 3 + c) * 16 + (zz - 1)) * 12544 + (yy - 1) * 112 + (xx - 1)];
    xp[i] = f2bf(v);
}

// ================= fuse ALL layers in one dispatch =================
struct FuseArgs {
    const float* proj[5];
    const float* alpha[5];
    float* Wf[5];
    int K[5];
    int CO[5];
    int NT[5];
    int start[6];
};

__global__ __launch_bounds__(256) void fuse_all(FuseArgs a)
{
    __shared__ __align__(16) float sa[16][64];  // [p][o]
    __shared__ __align__(16) float sp[16][64];  // [p][k]

    int l = 0;
    {
        const int bx = blockIdx.x;
        while (l < 4 && bx >= a.start[l + 1]) ++l;
    }
    const int idx = blockIdx.x - a.start[l];
    const int NT = a.NT[l];
    const int obase = (idx / NT) * 64;
    const int kbase = (idx % NT) * 64;
    const int K = a.K[l], CO = a.CO[l];
    const float* __restrict__ proj  = a.proj[l];
    const float* __restrict__ alpha = a.alpha[l];
    float* __restrict__ Wf = a.Wf[l];

    const int tid = threadIdx.x;
    const int tk = tid & 15, to = tid >> 4;

    const int pp  = tid >> 4;
    const int col = (tid & 15) * 4;
    const int o_st = obase + col;
    const int k_st = kbase + col;
    const bool a_ok  = (o_st < CO);
    const bool p_vec = ((K & 3) == 0) && (k_st + 4 <= K);

    float acc[4][4];
    #pragma unroll
    for (int i = 0; i < 4; ++i)
        #pragma unroll
        for (int j = 0; j < 4; ++j) acc[i][j] = 0.f;

    for (int p0 = 0; p0 < 512; p0 += 16) {
        const float* ap  = alpha + (size_t)(p0 + pp) * CO;
        const float* prp = proj  + (size_t)(p0 + pp) * K;
        float4 va = make_float4(0.f, 0.f, 0.f, 0.f);
        float4 vp = make_float4(0.f, 0.f, 0.f, 0.f);
        if (a_ok) va = *(const float4*)(ap + o_st);
        if (p_vec) {
            vp = *(const float4*)(prp + k_st);
        } else {
            float t4[4];
            #pragma unroll
            for (int j = 0; j < 4; ++j)
                t4[j] = (k_st + j < K) ? prp[k_st + j] : 0.f;
            vp = make_float4(t4[0], t4[1], t4[2], t4[3]);
        }
        *(float4*)&sa[pp][col] = va;
        *(float4*)&sp[pp][col] = vp;
        __syncthreads();
        #pragma unroll
        for (int p = 0; p < 16; ++p) {
            const float4 a4 = *(const float4*)&sa[p][to * 4];
            const float4 b4 = *(const float4*)&sp[p][tk * 4];
            const float aa[4] = {a4.x, a4.y, a4.z, a4.w};
            const float bb[4] = {b4.x, b4.y, b4.z, b4.w};
            #pragma unroll
            for (int i = 0; i < 4; ++i)
                #pragma unroll
                for (int j = 0; j < 4; ++j)
                    acc[i][j] = fmaf(aa[i], bb[j], acc[i][j]);
        }
        __syncthreads();
    }

    #pragma unroll
    for (int i = 0; i < 4; ++i) {
        const int o = obase + to * 4 + i;
        if (o < CO) {
            #pragma unroll
            for (int j = 0; j < 4; ++j) {
                const int kk = kbase + tk * 4 + j;
                if (kk < K) Wf[(size_t)o * K + kk] = acc[i][j];
            }
        }
    }
}

// ================= reorder ALL layers in one dispatch =================
struct ReordArgs {
    const float* Wf[5];
    unsigned short* Wb[5];
    int K[5], CPAD[5], KPAD[5], CO[5];
    int start[6];
};

__global__ __launch_bounds__(256) void reorder_all(ReordArgs a)
{
    int l = 0;
    {
        const int bx = blockIdx.x;
        while (l < 4 && bx >= a.start[l + 1]) ++l;
    }
    const int o = blockIdx.x - a.start[l];
    const int K = a.K[l], CPAD = a.CPAD[l], KPAD = a.KPAD[l], CO = a.CO[l];
    const int tid = threadIdx.x;
    unsigned short* row = a.Wb[l] + (size_t)o * KPAD;
    for (int i = tid; i < KPAD; i += 256) row[i] = 0;
    __syncthreads();
    if (o < CO) {
        const float* wr = a.Wf[l] + (size_t)o * K;
        for (int k = tid; k < K; k += 256) {
            const int c = k / 27, s = k - c * 27;
            row[s * CPAD + c] = f2bf(wr[k]);
        }
    }
}

// ================= implicit-GEMM MFMA conv + clamp(1+x,0) + pool(1,2,2) + fused BN stats =================
// SPLIT==1: writes pre-BN fp32 flat [pooled][COUT] AND accumulates per-channel
// sum/sumsq into bnp rows (64 x 768: [row][c]=sum, [row][384+c]=sumsq).
template<int CPAD, int COUT, int KPAD, int HI, int WI, int HP, int WP, int NBLK, int SPLIT>
__global__ __launch_bounds__(256) void conv_mfma(
    const unsigned short* __restrict__ in, const unsigned short* __restrict__ Wb,
    float* __restrict__ outf, float* __restrict__ part, float* __restrict__ bnp)
{
    constexpr int NT = NBLK / 16;
    constexpr int HI2 = HI + 2, WI2 = WI + 2;
    constexpr bool C8 = (CPAD % 8 == 0);
    constexpr int TABN = C8 ? KPAD / 8 : KPAD / 4;
    constexpr int NSTEP = KPAD / 32 / SPLIT;
    constexpr int MTOT = 2 * 16 * HP * WP * 4;

    __shared__ __align__(16) unsigned short As[64 * 40];
    __shared__ __align__(16) unsigned short Bs[NBLK * 40];
    __shared__ int tab[TABN];
    __shared__ float bs[(SPLIT == 1) ? 2 * NBLK : 1];

    const int tid = threadIdx.x;
    const int lane = tid & 63;
    const int wv = tid >> 6;
    const int blk_m = blockIdx.x;
    const int oc0 = blockIdx.y * NBLK;
    const int kc = (SPLIT > 1) ? blockIdx.z : 0;

    for (int i = tid; i < TABN; i += 256) {
        const int k = i * (C8 ? 8 : 4);
        const int s = k / CPAD, c = k % CPAD;
        tab[i] = (s < 27) ? ((((s / 9) * HI2 + (s % 9) / 3) * WI2 + (s % 3)) * CPAD + c) : -1;
    }

    const int m_l = tid & 63;
    const int oct = tid >> 6;
    const int m_g = blk_m * 64 + m_l;
    const int pooled = m_g >> 2, sub = m_g & 3;
    const int pw_g = pooled % WP;
    const int ph_g = (pooled / WP) % HP;
    const int d_g  = (pooled / (WP * HP)) & 15;
    const int b_g  = pooled / (WP * HP * 16);
    const int h_g = 2 * ph_g + (sub >> 1);
    const int w_g = 2 * pw_g + (sub & 1);
    const size_t base_m = ((((size_t)b_g * 18 + d_g) * HI2 + h_g) * WI2 + w_g) * CPAD;

    f32x4 acc[NT];
    #pragma unroll
    for (int i = 0; i < NT; ++i) acc[i] = (f32x4){0.f, 0.f, 0.f, 0.f};

    const int k_begin = kc * NSTEP * 32;
    __syncthreads();

    for (int s = 0; s < NSTEP; ++s) {
        const int k0 = k_begin + s * 32;
        if constexpr (C8) {
            const int off = tab[(k0 >> 3) + oct];
            sh8 av = (sh8){0, 0, 0, 0, 0, 0, 0, 0};
            if (off >= 0) av = *(const sh8*)(in + base_m + off);
            *(sh8*)&As[m_l * 40 + oct * 8] = av;
        } else {
            #pragma unroll
            for (int hh = 0; hh < 2; ++hh) {
                const int off = tab[(k0 >> 2) + oct * 2 + hh];
                sh4 av = (sh4){0, 0, 0, 0};
                if (off >= 0) av = *(const sh4*)(in + base_m + off);
                *(sh4*)&As[m_l * 40 + oct * 8 + hh * 4] = av;
            }
        }
        for (int i = tid; i < NBLK * 4; i += 256) {
            const int row = i >> 2, cc = i & 3;
            *(sh8*)&Bs[row * 40 + cc * 8] =
                *(const sh8*)&Wb[(size_t)(oc0 + row) * KPAD + k0 + cc * 8];
        }
        __syncthreads();
        const sh8 af = *(const sh8*)&As[(wv * 16 + (lane & 15)) * 40 + (lane >> 4) * 8];
        #pragma unroll
        for (int nt = 0; nt < NT; ++nt) {
            const sh8 bf = *(const sh8*)&Bs[(nt * 16 + (lane & 15)) * 40 + (lane >> 4) * 8];
            acc[nt] = __builtin_amdgcn_mfma_f32_16x16x32_bf16(af, bf, acc[nt], 0, 0, 0);
        }
        __syncthreads();
    }

    const int q = lane >> 4;
    const int nloc = lane & 15;
    if constexpr (SPLIT == 1) {
        for (int i = tid; i < 2 * NBLK; i += 256) bs[i] = 0.f;
        __syncthreads();
        const int pooled_o = blk_m * 16 + wv * 4 + q;
        #pragma unroll
        for (int nt = 0; nt < NT; ++nt) {
            const int oc = oc0 + nt * 16 + nloc;
            float mx = fmaxf(1.f + acc[nt][0], 0.f);
            mx = fmaxf(mx, fmaxf(1.f + acc[nt][1], 0.f));
            mx = fmaxf(mx, fmaxf(1.f + acc[nt][2], 0.f));
            mx = fmaxf(mx, fmaxf(1.f + acc[nt][3], 0.f));
            float s1 = 0.f;
            if (oc < COUT) {
                outf[(size_t)pooled_o * COUT + oc] = mx;
                s1 = mx;
            }
            float s2 = s1 * s1;
            // reduce over the wave's 4 pooled positions (lane quads)
            s1 += __shfl_xor(s1, 16);
            s1 += __shfl_xor(s1, 32);
            s2 += __shfl_xor(s2, 16);
            s2 += __shfl_xor(s2, 32);
            if (q == 0) {
                atomicAdd(&bs[nt * 16 + nloc], s1);
                atomicAdd(&bs[NBLK + nt * 16 + nloc], s2);
            }
        }
        __syncthreads();
        float* rowp = bnp + (size_t)(blk_m & 63) * 768;
        for (int i = tid; i < NBLK; i += 256) {
            const int oc = oc0 + i;
            if (oc < COUT) {
                atomicAdd(&rowp[oc], bs[i]);
                atomicAdd(&rowp[384 + oc], bs[NBLK + i]);
            }
        }
    } else {
        #pragma unroll
        for (int nt = 0; nt < NT; ++nt) {
            const int oc = oc0 + nt * 16 + nloc;
            #pragma unroll
            for (int r = 0; r < 4; ++r) {
                const int mm = blk_m * 64 + wv * 16 + q * 4 + r;
                part[((size_t)kc * MTOT + mm) * COUT + oc] = acc[nt][r];
            }
        }
    }
}

// ================= split-K reduce + clamp + pool + fused BN stats =================
template<int COUT, int HP, int WP, int SPLIT>
__global__ __launch_bounds__(256) void pool_epi(const float* __restrict__ part,
                                                float* __restrict__ outf,
                                                float* __restrict__ bnp)
{
    constexpr int PO = 2 * 16 * HP * WP;
    constexpr int M = PO * 4;
    __shared__ float bs[2 * COUT];
    const int tid = threadIdx.x;
    for (int i = tid; i < 2 * COUT; i += 256) bs[i] = 0.f;
    __syncthreads();
    const int idx = blockIdx.x * 256 + tid;
    if (idx < PO * COUT) {
        const int oc = idx % COUT;
        const int p = idx / COUT;
        float v[4] = {0.f, 0.f, 0.f, 0.f};
        for (int s = 0; s < SPLIT; ++s)
            #pragma unroll
            for (int r = 0; r < 4; ++r)
                v[r] += part[((size_t)s * M + p * 4 + r) * COUT + oc];
        float mx = fmaxf(1.f + v[0], 0.f);
        mx = fmaxf(mx, fmaxf(1.f + v[1], 0.f));
        mx = fmaxf(mx, fmaxf(1.f + v[2], 0.f));
        mx = fmaxf(mx, fmaxf(1.f + v[3], 0.f));
        outf[(size_t)p * COUT + oc] = mx;
        atomicAdd(&bs[oc], mx);
        atomicAdd(&bs[COUT + oc], mx * mx);
    }
    __syncthreads();
    float* rowp = bnp + (size_t)(blockIdx.x & 63) * 768;
    for (int i = tid; i < COUT; i += 256) {
        atomicAdd(&rowp[i], bs[i]);
        atomicAdd(&rowp[384 + i], bs[COUT + i]);
    }
}

// ================= BN reduce: sum 64 bnp rows per channel, compute st, re-zero =================
__global__ __launch_bounds__(64) void bn_reduce(float* __restrict__ bnp,
                                                const float* __restrict__ gamma,
                                                const float* __restrict__ beta,
                                                float* __restrict__ st,
                                                float inv_n)
{
    const int c = blockIdx.x, tid = threadIdx.x;
    float s = bnp[(size_t)tid * 768 + c];
    float q = bnp[(size_t)tid * 768 + 384 + c];
    bnp[(size_t)tid * 768 + c] = 0.f;
    bnp[(size_t)tid * 768 + 384 + c] = 0.f;
    #pragma unroll
    for (int off = 32; off > 0; off >>= 1) {
        s += __shfl_down(s, off);
        q += __shfl_down(q, off);
    }
    if (tid == 0) {
        const float mean = s * inv_n;
        const float var  = q * inv_n - mean * mean;
        const float sc   = gamma[c] * rsqrtf(var + EPS_BN);
        st[2 * c]     = sc;
        st[2 * c + 1] = fmaf(-mean, sc, beta[c]);
    }
}

// ================= BN apply: pre-BN fp32 flat -> bf16 halo interior =================
template<int C, int HP, int WP>
__global__ __launch_bounds__(256) void bn_apply_halo(const float* __restrict__ pre,
                                                     const float* __restrict__ st,
                                                     unsigned short* __restrict__ outh)
{
    constexpr int PO = 2 * 16 * HP * WP;
    const int idx = blockIdx.x * 256 + threadIdx.x;
    if (idx >= PO * C) return;
    const int c = idx % C;
    const int p = idx / C;
    const int pw = p % WP;
    const int ph = (p / WP) % HP;
    const int d  = (p / (WP * HP)) & 15;
    const int b  = p / (WP * HP * 16);
    const float v = fmaf(pre[idx], st[2 * c], st[2 * c + 1]);
    outh[((((size_t)b * 18 + d + 1) * (HP + 2) + ph + 1) * (WP + 2) + pw + 1) * C + c] = f2bf(v);
}

// ================= L5: flat pre-BN fp32 + BN -> NCDHW flat fp32 for fc1 =================
__global__ __launch_bounds__(256) void transpose5(const float* __restrict__ out5,
                                                  const float* __restrict__ st,
                                                  float* __restrict__ h)
{
    const int idx = blockIdx.x * 256 + threadIdx.x;
    if (idx >= 110592) return;
    const int c = idx % 384;
    const int p = idx / 384;
    const int b = p / 144;
    const int sp = p % 144;
    h[(size_t)b * 55296 + c * 144 + sp] = fmaf(out5[idx], st[2 * c], st[2 * c + 1]);
}

// ================= fc layers =================
__global__ __launch_bounds__(256) void fc1_k(const float* __restrict__ h,
                                             const float* __restrict__ w1,
                                             const float* __restrict__ b1,
                                             float* __restrict__ hout)
{
    __shared__ float r0[256];
    __shared__ float r1[256];
    const int j = blockIdx.x, tid = threadIdx.x;
    const float* wr = w1 + (size_t)j * 55296;
    float a0 = 0.f, a1 = 0.f;
    for (int k = tid * 4; k < 55296; k += 1024) {
        const float4 w = *(const float4*)(wr + k);
        const float4 u = *(const float4*)(h + k);
        const float4 v = *(const float4*)(h + 55296 + k);
        a0 += w.x * u.x + w.y * u.y + w.z * u.z + w.w * u.w;
        a1 += w.x * v.x + w.y * v.y + w.z * v.z + w.w * v.w;
    }
    r0[tid] = a0; r1[tid] = a1;
    __syncthreads();
    for (int off = 128; off > 0; off >>= 1) {
        if (tid < off) { r0[tid] += r0[tid + off]; r1[tid] += r1[tid + off]; }
        __syncthreads();
    }
    if (tid == 0) {
        hout[j]       = fmaxf(r0[0] + b1[j], 0.f);
        hout[512 + j] = fmaxf(r1[0] + b1[j], 0.f);
    }
}

__global__ __launch_bounds__(256) void fc23_k(const float* __restrict__ h1,
                                              const float* __restrict__ w2,
                                              const float* __restrict__ b2,
                                              const float* __restrict__ w3,
                                              const float* __restrict__ b3,
                                              float* __restrict__ out)
{
    __shared__ float h1s[1024];
    __shared__ float h2[512];
    const int tid = threadIdx.x;
    for (int i = tid; i < 1024; i += 256) h1s[i] = h1[i];
    __syncthreads();
    {
        const float* wr = w2 + (size_t)tid * 512;
        #pragma unroll
        for (int b = 0; b < 2; ++b) {
            float a = 0.f;
            const float* hh = h1s + b * 512;
            for (int k = 0; k < 512; ++k) a = fmaf(wr[k], hh[k], a);
            h2[b * 256 + tid] = fmaxf(a + b2[tid], 0.f);
        }
    }
    __syncthreads();
    if (tid < 101) {
        const float* wr = w3 + (size_t)tid * 256;
        #pragma unroll
        for (int b = 0; b < 2; ++b) {
            float a = 0.f;
            const float* hh = h2 + b * 256;
            for (int k = 0; k < 256; ++k) a = fmaf(wr[k], hh[k], a);
            out[b * 101 + tid] = a + b3[tid];
        }
    }
}

// ================= host =================
extern "C" void kernel_launch(void* const* d_in, const int* in_sizes, int n_in,
                              void* d_out, int out_size, void* d_ws, size_t ws_size,
                              hipStream_t stream)
{
    const float* x  = (const float*)d_in[0];
    const float* p[5], *al[5], *g[5], *q[5];
    for (int i = 0; i < 5; ++i) {
        p[i]  = (const float*)d_in[1 + 4 * i];
        al[i] = (const float*)d_in[2 + 4 * i];
        g[i]  = (const float*)d_in[3 + 4 * i];
        q[i]  = (const float*)d_in[4 + 4 * i];
    }
    const float* w1 = (const float*)d_in[21];
    const float* b1 = (const float*)d_in[22];
    const float* w2 = (const float*)d_in[23];
    const float* b2 = (const float*)d_in[24];
    const float* w3 = (const float*)d_in[25];
    const float* b3 = (const float*)d_in[26];

    float* ws = nullptr;
    hipGetSymbolAddress((void**)&ws, HIP_SYMBOL(g_ws));
    unsigned short* act = nullptr;
    hipGetSymbolAddress((void**)&act, HIP_SYMBOL(g_act));
    unsigned short* wb = nullptr;
    hipGetSymbolAddress((void**)&wb, HIP_SYMBOL(g_wb));

    float* Wf[5];
    for (int i = 0; i < 5; ++i) Wf[i] = ws + WF_OFF[i];
    float* part = ws + PART_OFF;
    float* pre  = ws + PRE_OFF;
    float* out5 = ws + OUT5_OFF;
    float* h    = ws + H_OFF;
    float* st   = ws + ST_OFF;
    float* bnp  = ws + BNP_OFF;
    float* h1   = ws + H1_OFF;

    unsigned short* xin = act + XIN_OFF;
    unsigned short* a1  = act + A1_OFF;
    unsigned short* a2  = act + A2_OFF;
    unsigned short* a3  = act + A3_OFF;
    unsigned short* a4  = act + A4_OFF;

    // zero bf16 activation halos for A1..A4 (xin fully written by convert_input)
    {
        const int n16 = (int)((AR_TOT - A1_OFF) * 2 / 16);
        zero16<<<(n16 + 255) / 256, 256, 0, stream>>>((int4*)(act + A1_OFF), n16);
    }
    convert_input<<<(2 * 18 * 114 * 114 * 4 + 255) / 256, 256, 0, stream>>>(x, xin, bnp);

    static const int KF[5] = {81, 648, 1296, 2592, 5184};
    static const int CO[5] = {24, 48, 96, 192, 384};
    static const int CP[5] = {4, 24, 48, 96, 192};
    static const int KP[5] = {128, 672, 1312, 2592, 5184};
    static const int NPAD[5] = {32, 48, 96, 192, 384};

    FuseArgs fa;
    int s0 = 0;
    for (int i = 0; i < 5; ++i) {
        fa.proj[i] = p[i]; fa.alpha[i] = al[i]; fa.Wf[i] = Wf[i];
        fa.K[i] = KF[i]; fa.CO[i] = CO[i];
        const int nt = (KF[i] + 63) / 64;
        const int mt = (CO[i] + 63) / 64;
        fa.NT[i] = nt;
        fa.start[i] = s0;
        s0 += nt * mt;
    }
    fa.start[5] = s0;
    fuse_all<<<s0, 256, 0, stream>>>(fa);

    ReordArgs ra;
    int r0 = 0;
    for (int i = 0; i < 5; ++i) {
        ra.Wf[i] = Wf[i]; ra.Wb[i] = wb + WB_OFF[i];
        ra.K[i] = KF[i]; ra.CPAD[i] = CP[i]; ra.KPAD[i] = KP[i]; ra.CO[i] = CO[i];
        ra.start[i] = r0;
        r0 += NPAD[i];
    }
    ra.start[5] = r0;
    reorder_all<<<r0, 256, 0, stream>>>(ra);

    // ---- L1 ----
    conv_mfma<4, 24, 128, 112, 112, 56, 56, 32, 1>
        <<<dim3(6272, 1), 256, 0, stream>>>(xin, wb + WB_OFF[0], pre, nullptr, bnp);
    bn_reduce<<<24, 64, 0, stream>>>(bnp, g[0], q[0], st, 1.f / 100352.f);
    bn_apply_halo<24, 56, 56><<<9408, 256, 0, stream>>>(pre, st, a1);

    // ---- L2 ----
    conv_mfma<24, 48, 672, 56, 56, 28, 28, 48, 1>
        <<<dim3(1568, 1), 256, 0, stream>>>(a1, wb + WB_OFF[1], pre, nullptr, bnp);
    bn_reduce<<<48, 64, 0, stream>>>(bnp, g[1], q[1], st, 1.f / 25088.f);
    bn_apply_halo<48, 28, 28><<<4704, 256, 0, stream>>>(pre, st, a2);

    // ---- L3 ----
    conv_mfma<48, 96, 1312, 28, 28, 14, 14, 48, 1>
        <<<dim3(392, 2), 256, 0, stream>>>(a2, wb + WB_OFF[2], pre, nullptr, bnp);
    bn_reduce<<<96, 64, 0, stream>>>(bnp, g[2], q[2], st, 1.f / 6272.f);
    bn_apply_halo<96, 14, 14><<<2352, 256, 0, stream>>>(pre, st, a3);

    // ---- L4 (split-K 3) ----
    conv_mfma<96, 192, 2592, 14, 14, 7, 7, 64, 3>
        <<<dim3(98, 3, 3), 256, 0, stream>>>(a3, wb + WB_OFF[3], nullptr, part, bnp);
    pool_epi<192, 7, 7, 3><<<1176, 256, 0, stream>>>(part, pre, bnp);
    bn_reduce<<<192, 64, 0, stream>>>(bnp, g[3], q[3], st, 1.f / 1568.f);
    bn_apply_halo<192, 7, 7><<<1176, 256, 0, stream>>>(pre, st, a4);

    // ---- L5 (split-K 6) ----
    conv_mfma<192, 384, 5184, 7, 7, 3, 3, 64, 6>
        <<<dim3(18, 6, 6), 256, 0, stream>>>(a4, wb + WB_OFF[4], nullptr, part, bnp);
    pool_epi<384, 3, 3, 6><<<432, 256, 0, stream>>>(part, out5, bnp);
    bn_reduce<<<384, 64, 0, stream>>>(bnp, g[4], q[4], st, 1.f / 288.f);

    // ---- head ----
    transpose5<<<(110592 + 255) / 256, 256, 0, stream>>>(out5, st, h);
    fc1_k<<<512, 256, 0, stream>>>(h, w1, b1, h1);
    fc23_k<<<1, 256, 0, stream>>>(h1, w2, b2, w3, b3, (float*)d_out);
}